// Round 3
// baseline (2408.650 us; speedup 1.0000x reference)
//
#include <hip/hip_runtime.h>
#include <math.h>

#define NB 4
#define NS 1024
#define ND 1024
#define NH 16
#define NDH 64

__device__ __forceinline__ unsigned short f2b(float f) {
    unsigned u = __float_as_uint(f);
    unsigned r = (u + 0x7fffu + ((u >> 16) & 1u)) >> 16;   // RNE
    return (unsigned short)r;
}
__device__ __forceinline__ float b2f(unsigned short h) {
    return __uint_as_float(((unsigned)h) << 16);
}

// ---------------------------------------------------------------------------
// Kernel 1: q projection with variance propagation.
//   q     = x @ Wm^T
//   var_q = var_x @ (Wv + Wm^2)^T + x^2 @ Wv^T
// Output written in [B,H,S,DH] layout into workspace.
// ---------------------------------------------------------------------------
__global__ __launch_bounds__(256)
void qproj_kernel(const float* __restrict__ x, const float* __restrict__ vx,
                  const float* __restrict__ Wm, const float* __restrict__ Wv,
                  float* __restrict__ q_ws, float* __restrict__ vq_ws)
{
    __shared__ float sX[16][64];
    __shared__ float sVX[16][64];
    __shared__ float sWM[16][64];
    __shared__ float sWV[16][64];

    const int tid = threadIdx.x;
    const int tn = tid & 15;
    const int tm = tid >> 4;
    const int n0 = blockIdx.x * 64;
    const int m0 = blockIdx.y * 64;
    const int lr = tid >> 2;
    const int lk = (tid & 3) << 2;

    float accq[4][4] = {};
    float accv[4][4] = {};

    const float* xrow  = x  + (size_t)(m0 + lr) * ND + lk;
    const float* vrow  = vx + (size_t)(m0 + lr) * ND + lk;
    const float* wmrow = Wm + (size_t)(n0 + lr) * ND + lk;
    const float* wvrow = Wv + (size_t)(n0 + lr) * ND + lk;

    for (int kt = 0; kt < ND / 16; ++kt) {
        const float4 xa  = *(const float4*)(xrow  + kt * 16);
        const float4 va  = *(const float4*)(vrow  + kt * 16);
        const float4 wm4 = *(const float4*)(wmrow + kt * 16);
        const float4 wv4 = *(const float4*)(wvrow + kt * 16);
        __syncthreads();
        sX [lk+0][lr] = xa.x;  sX [lk+1][lr] = xa.y;  sX [lk+2][lr] = xa.z;  sX [lk+3][lr] = xa.w;
        sVX[lk+0][lr] = va.x;  sVX[lk+1][lr] = va.y;  sVX[lk+2][lr] = va.z;  sVX[lk+3][lr] = va.w;
        sWM[lk+0][lr] = wm4.x; sWM[lk+1][lr] = wm4.y; sWM[lk+2][lr] = wm4.z; sWM[lk+3][lr] = wm4.w;
        sWV[lk+0][lr] = wv4.x; sWV[lk+1][lr] = wv4.y; sWV[lk+2][lr] = wv4.z; sWV[lk+3][lr] = wv4.w;
        __syncthreads();
        #pragma unroll
        for (int kk = 0; kk < 16; ++kk) {
            float ax[4], av[4], bm[4], bv[4], bw2[4];
            *(float4*)ax = *(const float4*)&sX [kk][tm << 2];
            *(float4*)av = *(const float4*)&sVX[kk][tm << 2];
            *(float4*)bm = *(const float4*)&sWM[kk][tn << 2];
            *(float4*)bv = *(const float4*)&sWV[kk][tn << 2];
            #pragma unroll
            for (int j = 0; j < 4; ++j) bw2[j] = fmaf(bm[j], bm[j], bv[j]);
            #pragma unroll
            for (int i = 0; i < 4; ++i) {
                const float xx = ax[i] * ax[i];
                #pragma unroll
                for (int j = 0; j < 4; ++j) {
                    accq[i][j] = fmaf(ax[i], bm[j], accq[i][j]);
                    accv[i][j] = fmaf(av[i], bw2[j], fmaf(xx, bv[j], accv[i][j]));
                }
            }
        }
    }

    const int h = blockIdx.x;
    #pragma unroll
    for (int i = 0; i < 4; ++i) {
        const int m = m0 + (tm << 2) + i;
        const int b = m >> 10;
        const int srow = m & 1023;
        const size_t o = (((size_t)b * NH + h) * NS + srow) * NDH + (tn << 2);
        *(float4*)(q_ws  + o) = make_float4(accq[i][0], accq[i][1], accq[i][2], accq[i][3]);
        *(float4*)(vq_ws + o) = make_float4(accv[i][0], accv[i][1], accv[i][2], accv[i][3]);
    }
}

// ---------------------------------------------------------------------------
// Kernel 2: fused causal attention with VDP variance propagation.
// LDS = 80 KiB -> 2 blocks/CU.  launch_bounds(512,2): VGPR cap 256 so the
// ~100 live floats/lane stay in registers (the (512,4) variant capped VGPR
// at 64 and spilled ~1.4 GB to scratch -> round-2 regression).
// ---------------------------------------------------------------------------
__global__ __launch_bounds__(512, 2)
void attn_vdp_kernel(const float* __restrict__ q_ws, const float* __restrict__ vq_ws,
                     const float* __restrict__ K,  const float* __restrict__ VK,
                     const float* __restrict__ Vv, const float* __restrict__ VV,
                     const float* __restrict__ x,
                     float* __restrict__ out0, float* __restrict__ out1)
{
    __shared__ float sQ[64][128];                 // 32 KiB: (q, var_q) fp32 pairs
    __shared__ unsigned short sKm [64][64];       // 8 KiB [dh][j^dh]  k mean
    __shared__ unsigned short sKk2[64][64];       // 8 KiB             k^2 + var_k
    __shared__ unsigned short sKv [64][64];       // 8 KiB             var_k
    __shared__ unsigned short sVm [64][64];       // 8 KiB [j][dh]     v mean
    __shared__ unsigned short sVw [64][64];       // 8 KiB             v^2 + var_v
    __shared__ unsigned short sVv [64][64];       // 8 KiB             var_v

    const int tid  = threadIdx.x;
    const int wv   = tid >> 6;
    const int lane = tid & 63;

    const int blk = blockIdx.x;
    const int qb  = 15 - (blk & 15);              // heavy blocks first
    const int bh  = blk >> 4;
    const int b   = bh >> 4;
    const int h   = bh & 15;
    const size_t kvbase = (size_t)bh * NS * NDH;
    const int row0 = qb * 64;

    // stage Q block (q, var_q interleaved fp32)
    #pragma unroll
    for (int it = 0; it < 8; ++it) {
        const int pos = tid + it * 512;
        const int r = pos >> 6, d = pos & 63;
        const size_t g = kvbase + (size_t)(row0 + r) * NDH + d;
        *(float2*)&sQ[r][d << 1] = make_float2(q_ws[g], vq_ws[g]);
    }

    float m_[8], Z_[8], S2_[8], N1[8], N2w[8], N2uw[8], N3uw[8], N2vv[8];
    #pragma unroll
    for (int r = 0; r < 8; ++r) {
        m_[r] = -INFINITY; Z_[r] = 0.f; S2_[r] = 0.f;
        N1[r] = 0.f; N2w[r] = 0.f; N2uw[r] = 0.f; N3uw[r] = 0.f; N2vv[r] = 0.f;
    }

    const int r0 = wv << 3;
    const int nt = qb + 1;
    for (int t = 0; t < nt; ++t) {
        const int j0 = t << 6;
        __syncthreads();   // previous tile fully consumed (also covers Q staging)
        #pragma unroll
        for (int it = 0; it < 8; ++it) {
            const int pos = tid + it * 512;
            const int jr = pos >> 6, d = pos & 63;
            const size_t g = kvbase + (size_t)(j0 + jr) * NDH + d;
            const float km = K[g],  kv = VK[g];
            const float vm = Vv[g], vv = VV[g];
            sKm [d][jr ^ d] = f2b(km);
            sKk2[d][jr ^ d] = f2b(fmaf(km, km, kv));
            sKv [d][jr ^ d] = f2b(kv);
            sVm[jr][d] = f2b(vm);
            sVw[jr][d] = f2b(fmaf(vm, vm, vv));
            sVv[jr][d] = f2b(vv);
        }
        __syncthreads();

        // ---- phase 1: lane = j, score mean/variance dots over dh ----
        float a_[8] = {}, u_[8] = {};
        #pragma unroll 8
        for (int dh = 0; dh < 64; ++dh) {
            const int c = lane ^ dh;
            const float km  = b2f(sKm [dh][c]);
            const float kk2 = b2f(sKk2[dh][c]);
            const float kv  = b2f(sKv [dh][c]);
            #pragma unroll
            for (int r = 0; r < 8; ++r) {
                const float2 qp = *(const float2*)&sQ[r0 + r][dh << 1];
                a_[r] = fmaf(qp.x, km, a_[r]);
                u_[r] = fmaf(qp.y, kk2, fmaf(qp.x * qp.x, kv, u_[r]));
            }
        }

        // ---- online softmax update per row (in-wave only) ----
        #pragma unroll
        for (int r = 0; r < 8; ++r) {
            const int irow = row0 + r0 + r;
            float a = a_[r] * 0.03125f;              // / sqrt(D)
            const float u = u_[r] * 0.0009765625f;   // / D
            if (j0 + lane > irow) a = -INFINITY;     // causal mask (mean path)
            float tmax = a;
            #pragma unroll
            for (int s_ = 32; s_; s_ >>= 1) tmax = fmaxf(tmax, __shfl_xor(tmax, s_));
            const float mnew = fmaxf(m_[r], tmax);
            const float e  = __expf(a - mnew);       // 0 for masked lanes
            const float s1 = __expf(m_[r] - mnew);
            m_[r] = mnew;
            float Zt = e, S2t = e * e * u;
            #pragma unroll
            for (int s_ = 32; s_; s_ >>= 1) { Zt += __shfl_xor(Zt, s_); S2t += __shfl_xor(S2t, s_); }
            const float s2 = s1 * s1, s3 = s2 * s1;
            Z_[r]  = fmaf(Z_[r],  s1, Zt);
            S2_[r] = fmaf(S2_[r], s2, S2t);
            N1[r] *= s1; N2w[r] *= s2; N2uw[r] *= s2; N3uw[r] *= s3; N2vv[r] *= s2;
            a_[r] = e;      // keep e in register (lane = j)
            u_[r] = u;      // keep u in register (lane = j)
        }

        // ---- phase 2: lane = dh; e,u broadcast from registers via readlane ----
        #pragma unroll 4
        for (int j = 0; j < 64; ++j) {
            const float vm = b2f(sVm[j][lane]);
            const float w  = b2f(sVw[j][lane]);
            const float vv = b2f(sVv[j][lane]);
            #pragma unroll
            for (int r = 0; r < 8; ++r) {
                const float ee = __uint_as_float(__builtin_amdgcn_readlane(__float_as_uint(a_[r]), j));
                const float uu = __uint_as_float(__builtin_amdgcn_readlane(__float_as_uint(u_[r]), j));
                const float c2  = ee * ee;
                const float c2u = c2 * uu;
                const float c3u = c2u * ee;
                N1[r]   = fmaf(ee,  vm, N1[r]);
                N2w[r]  = fmaf(c2,  w,  N2w[r]);
                N2uw[r] = fmaf(c2u, w,  N2uw[r]);
                N3uw[r] = fmaf(c3u, w,  N3uw[r]);
                N2vv[r] = fmaf(c2,  vv, N2vv[r]);
            }
        }
    }

    // epilogue
    #pragma unroll
    for (int r = 0; r < 8; ++r) {
        const int irow = row0 + r0 + r;
        const float rZ  = 1.0f / Z_[r];
        const float rZ2 = rZ * rZ;
        const float s   = S2_[r] * rZ2;
        const float Om  = N1[r] * rZ;
        const float Vo  = rZ2 * (fmaf(s, N2w[r], N2uw[r] + N2vv[r])) - 2.0f * rZ2 * rZ * N3uw[r];
        const size_t o = ((size_t)b * NS + irow) * ND + (h << 6) + lane;
        out0[o] = x[o] + Om;
        out1[o] = Vo;
    }
}

extern "C" void kernel_launch(void* const* d_in, const int* in_sizes, int n_in,
                              void* d_out, int out_size, void* d_ws, size_t ws_size,
                              hipStream_t stream)
{
    (void)in_sizes; (void)n_in; (void)out_size; (void)ws_size;
    const float* x  = (const float*)d_in[0];
    const float* vx = (const float*)d_in[1];
    const float* K  = (const float*)d_in[2];
    const float* VK = (const float*)d_in[3];
    const float* Vv = (const float*)d_in[4];
    const float* VV = (const float*)d_in[5];
    const float* Wm = (const float*)d_in[6];
    const float* Wv = (const float*)d_in[7];

    float* out0 = (float*)d_out;
    float* out1 = out0 + (size_t)NB * NS * ND;
    float* q_ws  = (float*)d_ws;
    float* vq_ws = q_ws + (size_t)NB * NH * NS * NDH;

    dim3 g1(ND / 64, (NB * NS) / 64);
    qproj_kernel<<<g1, 256, 0, stream>>>(x, vx, Wm, Wv, q_ws, vq_ws);
    attn_vdp_kernel<<<NB * NH * (NS / 64), 512, 0, stream>>>(q_ws, vq_ws, K, VK, Vv, VV, x, out0, out1);
}

// Round 4
// 418.102 us; speedup vs baseline: 5.7609x; 5.7609x over previous
//
#include <hip/hip_runtime.h>
#include <hip/hip_bf16.h>
#include <math.h>

#define NB 4
#define NS 1024
#define ND 1024
#define NH 16
#define NDH 64

typedef float f16v __attribute__((ext_vector_type(16)));
typedef short bf8 __attribute__((ext_vector_type(8)));

union U8 { bf8 v; unsigned u[4]; unsigned short s[8]; };

__device__ __forceinline__ unsigned pk(float lo, float hi) {
    __hip_bfloat162 h2 = __float22bfloat162_rn(make_float2(lo, hi));
    return *reinterpret_cast<unsigned*>(&h2);
}
__device__ __forceinline__ float b2f(unsigned short h) {
    return __uint_as_float(((unsigned)h) << 16);
}
__device__ __forceinline__ f16v zero16() {
    f16v z;
    #pragma unroll
    for (int i = 0; i < 16; ++i) z[i] = 0.f;
    return z;
}
__device__ __forceinline__ void vscale(f16v& v, float s) {
    #pragma unroll
    for (int i = 0; i < 16; ++i) v[i] *= s;
}

// Build PV B-frag (coef[j, r], K=16 chunk) from packed pairs p0..p3 = P[4c2..4c2+3].
// Target lane (r, h): dwords {d0,d1} from half h'=0 at index 4c2+2h, {d2,d3} from
// half h'=1 at the same index. Cross-half values fetched via shfl_xor(32) of the
// partner's wanted index.
__device__ __forceinline__ bf8 mkB(unsigned p0, unsigned p1, unsigned p2, unsigned p3, int h) {
    unsigned own0 = h ? p2 : p0;
    unsigned own1 = h ? p3 : p1;
    unsigned ct0  = h ? p0 : p2;
    unsigned ct1  = h ? p1 : p3;
    unsigned x0 = (unsigned)__shfl_xor((int)ct0, 32);
    unsigned x1 = (unsigned)__shfl_xor((int)ct1, 32);
    U8 B;
    B.u[0] = h ? x0 : own0;
    B.u[1] = h ? x1 : own1;
    B.u[2] = h ? own0 : x0;
    B.u[3] = h ? own1 : x1;
    return B.v;
}

// ---------------------------------------------------------------------------
// Kernel 1: q projection (MFMA, swapped: D[n, m] = W-rows x x-rows).
//   q = x@Wm^T ; var_q = vx@(Wv+Wm^2)^T + x^2@Wv^T
// Writes bf16 planes qm_ws, vq_ws in [B,H,S,DH] layout.
// ---------------------------------------------------------------------------
__global__ __launch_bounds__(256, 3)
void qproj_kernel(const float* __restrict__ x, const float* __restrict__ vx,
                  const float* __restrict__ Wm, const float* __restrict__ Wv,
                  unsigned short* __restrict__ qm_ws, unsigned short* __restrict__ vq_ws)
{
    const int tid  = threadIdx.x;
    const int w    = tid >> 6;
    const int lane = tid & 63;
    const int lh   = lane & 31;
    const int h    = lane >> 5;
    const int head = blockIdx.x;            // 0..15
    const int mb   = blockIdx.y;            // 0..31
    const int mrow = mb * 128 + w * 32 + lh; // global s-row (B-frag col)

    f16v aQ0 = zero16(), aQ1 = zero16(), aV0 = zero16(), aV1 = zero16();

    const float* xr = x  + (size_t)mrow * ND;
    const float* vr = vx + (size_t)mrow * ND;
    const float* w0 = Wm + (size_t)(head * 64 +      lh) * ND;
    const float* w1 = Wm + (size_t)(head * 64 + 32 + lh) * ND;
    const float* v0 = Wv + (size_t)(head * 64 +      lh) * ND;
    const float* v1 = Wv + (size_t)(head * 64 + 32 + lh) * ND;

    for (int kc = 0; kc < 64; ++kc) {
        const int ko = kc * 16 + 8 * h;
        // B-frags (x side): fx, fvx, fx2
        float4 xa = *(const float4*)(xr + ko); float4 xb = *(const float4*)(xr + ko + 4);
        float4 va = *(const float4*)(vr + ko); float4 vb = *(const float4*)(vr + ko + 4);
        U8 fx, fvx, fx2;
        fx.u[0]  = pk(xa.x, xa.y); fx.u[1]  = pk(xa.z, xa.w);
        fx.u[2]  = pk(xb.x, xb.y); fx.u[3]  = pk(xb.z, xb.w);
        fvx.u[0] = pk(va.x, va.y); fvx.u[1] = pk(va.z, va.w);
        fvx.u[2] = pk(vb.x, vb.y); fvx.u[3] = pk(vb.z, vb.w);
        fx2.u[0] = pk(xa.x*xa.x, xa.y*xa.y); fx2.u[1] = pk(xa.z*xa.z, xa.w*xa.w);
        fx2.u[2] = pk(xb.x*xb.x, xb.y*xb.y); fx2.u[3] = pk(xb.z*xb.z, xb.w*xb.w);
        // A-frags nt=0
        {
            float4 ma = *(const float4*)(w0 + ko); float4 mb4 = *(const float4*)(w0 + ko + 4);
            float4 wa = *(const float4*)(v0 + ko); float4 wb  = *(const float4*)(v0 + ko + 4);
            U8 fm, fw2, fv;
            fm.u[0]  = pk(ma.x, ma.y);  fm.u[1]  = pk(ma.z, ma.w);
            fm.u[2]  = pk(mb4.x, mb4.y); fm.u[3] = pk(mb4.z, mb4.w);
            fv.u[0]  = pk(wa.x, wa.y);  fv.u[1]  = pk(wa.z, wa.w);
            fv.u[2]  = pk(wb.x, wb.y);  fv.u[3]  = pk(wb.z, wb.w);
            fw2.u[0] = pk(fmaf(ma.x,ma.x,wa.x),  fmaf(ma.y,ma.y,wa.y));
            fw2.u[1] = pk(fmaf(ma.z,ma.z,wa.z),  fmaf(ma.w,ma.w,wa.w));
            fw2.u[2] = pk(fmaf(mb4.x,mb4.x,wb.x), fmaf(mb4.y,mb4.y,wb.y));
            fw2.u[3] = pk(fmaf(mb4.z,mb4.z,wb.z), fmaf(mb4.w,mb4.w,wb.w));
            aQ0 = __builtin_amdgcn_mfma_f32_32x32x16_bf16(fm.v,  fx.v,  aQ0, 0, 0, 0);
            aV0 = __builtin_amdgcn_mfma_f32_32x32x16_bf16(fw2.v, fvx.v, aV0, 0, 0, 0);
            aV0 = __builtin_amdgcn_mfma_f32_32x32x16_bf16(fv.v,  fx2.v, aV0, 0, 0, 0);
        }
        // A-frags nt=1
        {
            float4 ma = *(const float4*)(w1 + ko); float4 mb4 = *(const float4*)(w1 + ko + 4);
            float4 wa = *(const float4*)(v1 + ko); float4 wb  = *(const float4*)(v1 + ko + 4);
            U8 fm, fw2, fv;
            fm.u[0]  = pk(ma.x, ma.y);  fm.u[1]  = pk(ma.z, ma.w);
            fm.u[2]  = pk(mb4.x, mb4.y); fm.u[3] = pk(mb4.z, mb4.w);
            fv.u[0]  = pk(wa.x, wa.y);  fv.u[1]  = pk(wa.z, wa.w);
            fv.u[2]  = pk(wb.x, wb.y);  fv.u[3]  = pk(wb.z, wb.w);
            fw2.u[0] = pk(fmaf(ma.x,ma.x,wa.x),  fmaf(ma.y,ma.y,wa.y));
            fw2.u[1] = pk(fmaf(ma.z,ma.z,wa.z),  fmaf(ma.w,ma.w,wa.w));
            fw2.u[2] = pk(fmaf(mb4.x,mb4.x,wb.x), fmaf(mb4.y,mb4.y,wb.y));
            fw2.u[3] = pk(fmaf(mb4.z,mb4.z,wb.z), fmaf(mb4.w,mb4.w,wb.w));
            aQ1 = __builtin_amdgcn_mfma_f32_32x32x16_bf16(fm.v,  fx.v,  aQ1, 0, 0, 0);
            aV1 = __builtin_amdgcn_mfma_f32_32x32x16_bf16(fw2.v, fvx.v, aV1, 0, 0, 0);
            aV1 = __builtin_amdgcn_mfma_f32_32x32x16_bf16(fv.v,  fx2.v, aV1, 0, 0, 0);
        }
    }

    // write: D[n, m] -> lane owns s-row mrow, 2x16 dh values; pack pairs, dword stores
    const int b = mrow >> 10, srow = mrow & 1023;
    unsigned short* qp = qm_ws + (((size_t)(b * NH + head)) * NS + srow) * NDH;
    unsigned short* vp = vq_ws + (((size_t)(b * NH + head)) * NS + srow) * NDH;
    #pragma unroll
    for (int i = 0; i < 16; i += 2) {
        const int dh0 = (i & 3) + 8 * (i >> 2) + 4 * h;
        *(unsigned*)(qp + dh0)      = pk(aQ0[i], aQ0[i+1]);
        *(unsigned*)(qp + 32 + dh0) = pk(aQ1[i], aQ1[i+1]);
        *(unsigned*)(vp + dh0)      = pk(aV0[i], aV0[i+1]);
        *(unsigned*)(vp + 32 + dh0) = pk(aV1[i], aV1[i+1]);
    }
}

// ---------------------------------------------------------------------------
// Kernel 2: fused causal VDP attention, MFMA 32x32x16, flash-style.
// No LDS / barriers in the main loop. Swapped scores S^T[j,r], swapped PV
// D[dh,r]. 4 accumulator sets: N1, N2w, (N2uw+N2vv), N3uw.
// ---------------------------------------------------------------------------
__global__ __launch_bounds__(256, 2)
void attn_vdp_kernel(const unsigned short* __restrict__ qm_ws,
                     const unsigned short* __restrict__ vq_ws,
                     const float* __restrict__ K,  const float* __restrict__ VK,
                     const float* __restrict__ Vv, const float* __restrict__ VV,
                     const float* __restrict__ x,
                     float* __restrict__ out0, float* __restrict__ out1)
{
    __shared__ float lds[128][65];

    const int tid  = threadIdx.x;
    const int w    = tid >> 6;
    const int lane = tid & 63;
    const int lh   = lane & 31;
    const int h    = lane >> 5;
    const int blk  = blockIdx.x;
    const int rb   = 7 - (blk & 7);          // heavy-first
    const int bh   = blk >> 3;
    const int row0 = rb * 128 + w * 32;
    const int rg   = row0 + lh;              // this lane's q-row (within bh)
    const size_t base = (size_t)bh * NS * NDH;

    // persistent Q B-frags (col r = lh): qm, vq, q^2
    bf8 fqm[4], fvq[4], fq2[4];
    {
        const unsigned short* qp = qm_ws + base + (size_t)rg * NDH;
        const unsigned short* vp = vq_ws + base + (size_t)rg * NDH;
        #pragma unroll
        for (int c = 0; c < 4; ++c) {
            fqm[c] = *(const bf8*)(qp + 16 * c + 8 * h);
            fvq[c] = *(const bf8*)(vp + 16 * c + 8 * h);
            U8 t; t.v = fqm[c];
            U8 r;
            #pragma unroll
            for (int k = 0; k < 4; ++k) {
                float q0 = b2f(t.s[2*k]), q1 = b2f(t.s[2*k+1]);
                r.u[k] = pk(q0 * q0, q1 * q1);
            }
            fq2[c] = r.v;
        }
    }

    f16v aN1[2], aN2w[2], aM2[2], aN3[2];
    #pragma unroll
    for (int dt = 0; dt < 2; ++dt) { aN1[dt] = zero16(); aN2w[dt] = zero16(); aM2[dt] = zero16(); aN3[dt] = zero16(); }
    float mrun = -INFINITY, Zrun = 0.f, S2run = 0.f;

    const int nsub = 4 * rb + w + 1;          // causal extent, 32-j subtiles
    for (int st = 0; st < nsub; ++st) {
        const int j0 = st * 32;
        // ---- phase 1: scores S^T[j, r] ----
        f16v accA = zero16(), accU = zero16();
        #pragma unroll
        for (int c = 0; c < 4; ++c) {
            const float* kp = K  + base + (size_t)(j0 + lh) * NDH + 16 * c + 8 * h;
            const float* up = VK + base + (size_t)(j0 + lh) * NDH + 16 * c + 8 * h;
            float4 k0 = *(const float4*)kp, k1 = *(const float4*)(kp + 4);
            float4 u0 = *(const float4*)up, u1 = *(const float4*)(up + 4);
            U8 fkm, fk2, fkv;
            fkm.u[0] = pk(k0.x, k0.y); fkm.u[1] = pk(k0.z, k0.w);
            fkm.u[2] = pk(k1.x, k1.y); fkm.u[3] = pk(k1.z, k1.w);
            fkv.u[0] = pk(u0.x, u0.y); fkv.u[1] = pk(u0.z, u0.w);
            fkv.u[2] = pk(u1.x, u1.y); fkv.u[3] = pk(u1.z, u1.w);
            fk2.u[0] = pk(fmaf(k0.x,k0.x,u0.x), fmaf(k0.y,k0.y,u0.y));
            fk2.u[1] = pk(fmaf(k0.z,k0.z,u0.z), fmaf(k0.w,k0.w,u0.w));
            fk2.u[2] = pk(fmaf(k1.x,k1.x,u1.x), fmaf(k1.y,k1.y,u1.y));
            fk2.u[3] = pk(fmaf(k1.z,k1.z,u1.z), fmaf(k1.w,k1.w,u1.w));
            accA = __builtin_amdgcn_mfma_f32_32x32x16_bf16(fkm.v, fqm[c], accA, 0, 0, 0);
            accU = __builtin_amdgcn_mfma_f32_32x32x16_bf16(fk2.v, fvq[c], accU, 0, 0, 0);
            accU = __builtin_amdgcn_mfma_f32_32x32x16_bf16(fkv.v, fq2[c], accU, 0, 0, 0);
        }
        float a[16], u[16];
        #pragma unroll
        for (int i = 0; i < 16; ++i) { a[i] = accA[i] * 0.03125f; u[i] = accU[i] * 0.0009765625f; }
        if (st == nsub - 1) {                 // diagonal subtile: mask j_loc > lh
            #pragma unroll
            for (int i = 0; i < 16; ++i) {
                const int jl = (i & 3) + 8 * (i >> 2) + 4 * h;
                if (jl > lh) a[i] = -INFINITY;
            }
        }
        // ---- online softmax (per r = lh; 1 cross-half shfl per reduction) ----
        float mx = a[0];
        #pragma unroll
        for (int i = 1; i < 16; ++i) mx = fmaxf(mx, a[i]);
        mx = fmaxf(mx, __shfl_xor(mx, 32));
        const float mnew = fmaxf(mrun, mx);
        const float s1 = __expf(mrun - mnew);
        float ex[16];
        float Zt = 0.f, St = 0.f;
        #pragma unroll
        for (int i = 0; i < 16; ++i) {
            float ee = __expf(a[i] - mnew);
            ex[i] = ee; Zt += ee; St = fmaf(ee * ee, u[i], St);
        }
        Zt += __shfl_xor(Zt, 32); St += __shfl_xor(St, 32);
        const float s2 = s1 * s1, s3 = s2 * s1;
        Zrun = fmaf(Zrun, s1, Zt); S2run = fmaf(S2run, s2, St); mrun = mnew;
        #pragma unroll
        for (int dt = 0; dt < 2; ++dt) { vscale(aN1[dt], s1); vscale(aN2w[dt], s2); vscale(aM2[dt], s2); vscale(aN3[dt], s3); }
        // ---- coefficient packs ----
        unsigned PE[8], PE2[8], PEU[8], PE3[8];
        #pragma unroll
        for (int k = 0; k < 8; ++k) {
            float e0 = ex[2*k], e1 = ex[2*k+1];
            float q0 = e0 * e0, q1 = e1 * e1;
            float t0 = q0 * u[2*k], t1 = q1 * u[2*k+1];
            PE[k]  = pk(e0, e1);
            PE2[k] = pk(q0, q1);
            PEU[k] = pk(t0, t1);
            PE3[k] = pk(t0 * e0, t1 * e1);
        }
        // ---- phase 2: PV, D[dh, r] ----
        #pragma unroll
        for (int c2 = 0; c2 < 2; ++c2) {
            bf8 BE  = mkB(PE [4*c2], PE [4*c2+1], PE [4*c2+2], PE [4*c2+3], h);
            bf8 BE2 = mkB(PE2[4*c2], PE2[4*c2+1], PE2[4*c2+2], PE2[4*c2+3], h);
            bf8 BEU = mkB(PEU[4*c2], PEU[4*c2+1], PEU[4*c2+2], PEU[4*c2+3], h);
            bf8 BE3 = mkB(PE3[4*c2], PE3[4*c2+1], PE3[4*c2+2], PE3[4*c2+3], h);
            #pragma unroll
            for (int dt = 0; dt < 2; ++dt) {
                const float* vmb = Vv + base + (size_t)(j0 + 16*c2 + 8*h) * NDH + 32*dt + lh;
                const float* vvb = VV + base + (size_t)(j0 + 16*c2 + 8*h) * NDH + 32*dt + lh;
                float vm[8], vv[8];
                #pragma unroll
                for (int e = 0; e < 8; ++e) { vm[e] = vmb[e * NDH]; vv[e] = vvb[e * NDH]; }
                U8 fvm, fw, fvv;
                #pragma unroll
                for (int k = 0; k < 4; ++k) {
                    float w0f = fmaf(vm[2*k],   vm[2*k],   vv[2*k]);
                    float w1f = fmaf(vm[2*k+1], vm[2*k+1], vv[2*k+1]);
                    fvm.u[k] = pk(vm[2*k], vm[2*k+1]);
                    fw.u[k]  = pk(w0f, w1f);
                    fvv.u[k] = pk(vv[2*k], vv[2*k+1]);
                }
                aN1[dt]  = __builtin_amdgcn_mfma_f32_32x32x16_bf16(fvm.v, BE,  aN1[dt],  0, 0, 0);
                aN2w[dt] = __builtin_amdgcn_mfma_f32_32x32x16_bf16(fw.v,  BE2, aN2w[dt], 0, 0, 0);
                aM2[dt]  = __builtin_amdgcn_mfma_f32_32x32x16_bf16(fw.v,  BEU, aM2[dt],  0, 0, 0);
                aM2[dt]  = __builtin_amdgcn_mfma_f32_32x32x16_bf16(fvv.v, BE2, aM2[dt],  0, 0, 0);
                aN3[dt]  = __builtin_amdgcn_mfma_f32_32x32x16_bf16(fw.v,  BE3, aN3[dt],  0, 0, 0);
            }
        }
    }

    // ---- epilogue: normalize, LDS transpose, coalesced writes ----
    const float rZ  = 1.f / Zrun;
    const float rZ2 = rZ * rZ;
    const float sS  = S2run * rZ2;
    const int b = bh >> 4, head = bh & 15;

    #pragma unroll
    for (int dt = 0; dt < 2; ++dt)
        #pragma unroll
        for (int i = 0; i < 16; ++i) {
            const int col = 32 * dt + (i & 3) + 8 * (i >> 2) + 4 * h;
            lds[w * 32 + lh][col] = aN1[dt][i] * rZ;
        }
    __syncthreads();
    {
        const int row = tid >> 1, half = (tid & 1) * 32;
        const size_t o = ((size_t)b * NS + rb * 128 + row) * ND + head * NDH + half;
        #pragma unroll
        for (int q4 = 0; q4 < 32; q4 += 4) {
            float4 t = make_float4(lds[row][half+q4], lds[row][half+q4+1],
                                   lds[row][half+q4+2], lds[row][half+q4+3]);
            float4 xi = *(const float4*)(x + o + q4);
            *(float4*)(out0 + o + q4) = make_float4(t.x+xi.x, t.y+xi.y, t.z+xi.z, t.w+xi.w);
        }
    }
    __syncthreads();
    #pragma unroll
    for (int dt = 0; dt < 2; ++dt)
        #pragma unroll
        for (int i = 0; i < 16; ++i) {
            const int col = 32 * dt + (i & 3) + 8 * (i >> 2) + 4 * h;
            lds[w * 32 + lh][col] = rZ2 * fmaf(sS, aN2w[dt][i], aM2[dt][i]) - 2.f * rZ2 * rZ * aN3[dt][i];
        }
    __syncthreads();
    {
        const int row = tid >> 1, half = (tid & 1) * 32;
        const size_t o = ((size_t)b * NS + rb * 128 + row) * ND + head * NDH + half;
        #pragma unroll
        for (int q4 = 0; q4 < 32; q4 += 4) {
            float4 t = make_float4(lds[row][half+q4], lds[row][half+q4+1],
                                   lds[row][half+q4+2], lds[row][half+q4+3]);
            *(float4*)(out1 + o + q4) = t;
        }
    }
}

extern "C" void kernel_launch(void* const* d_in, const int* in_sizes, int n_in,
                              void* d_out, int out_size, void* d_ws, size_t ws_size,
                              hipStream_t stream)
{
    (void)in_sizes; (void)n_in; (void)out_size; (void)ws_size;
    const float* x  = (const float*)d_in[0];
    const float* vx = (const float*)d_in[1];
    const float* K  = (const float*)d_in[2];
    const float* VK = (const float*)d_in[3];
    const float* Vv = (const float*)d_in[4];
    const float* VV = (const float*)d_in[5];
    const float* Wm = (const float*)d_in[6];
    const float* Wv = (const float*)d_in[7];

    float* out0 = (float*)d_out;
    float* out1 = out0 + (size_t)NB * NS * ND;
    unsigned short* qm_ws = (unsigned short*)d_ws;                       // 8 MB
    unsigned short* vq_ws = qm_ws + (size_t)NB * NH * NS * NDH;          // 8 MB

    qproj_kernel<<<dim3(NH, 32), 256, 0, stream>>>(x, vx, Wm, Wv, qm_ws, vq_ws);
    attn_vdp_kernel<<<64 * 8, 256, 0, stream>>>(qm_ws, vq_ws, K, VK, Vv, VV, x, out0, out1);
}

// Round 5
// 374.095 us; speedup vs baseline: 6.4386x; 1.1176x over previous
//
#include <hip/hip_runtime.h>
#include <hip/hip_bf16.h>
#include <math.h>

#define NB 4
#define NS 1024
#define ND 1024
#define NH 16
#define NDH 64

typedef float f16v __attribute__((ext_vector_type(16)));
typedef short bf8 __attribute__((ext_vector_type(8)));
typedef unsigned short ushort_t;

union U8 { bf8 v; unsigned u[4]; unsigned short s[8]; };

__device__ __forceinline__ unsigned pk(float lo, float hi) {
    __hip_bfloat162 h2 = __float22bfloat162_rn(make_float2(lo, hi));
    return *reinterpret_cast<unsigned*>(&h2);
}
__device__ __forceinline__ unsigned short f2b(float f) {
    unsigned u = __float_as_uint(f);
    unsigned r = (u + 0x7fffu + ((u >> 16) & 1u)) >> 16;   // RNE
    return (unsigned short)r;
}
__device__ __forceinline__ float b2f(unsigned short h) {
    return __uint_as_float(((unsigned)h) << 16);
}
__device__ __forceinline__ f16v zero16() {
    f16v z;
    #pragma unroll
    for (int i = 0; i < 16; ++i) z[i] = 0.f;
    return z;
}
__device__ __forceinline__ void vscale(f16v& v, float s) {
    #pragma unroll
    for (int i = 0; i < 16; ++i) v[i] *= s;
}

// Build PV B-frag (coef[j, r], K=16 chunk) from packed pairs p0..p3.
__device__ __forceinline__ bf8 mkB(unsigned p0, unsigned p1, unsigned p2, unsigned p3, int h) {
    unsigned own0 = h ? p2 : p0;
    unsigned own1 = h ? p3 : p1;
    unsigned ct0  = h ? p0 : p2;
    unsigned ct1  = h ? p1 : p3;
    unsigned x0 = (unsigned)__shfl_xor((int)ct0, 32);
    unsigned x1 = (unsigned)__shfl_xor((int)ct1, 32);
    U8 B;
    B.u[0] = h ? x0 : own0;
    B.u[1] = h ? x1 : own1;
    B.u[2] = h ? own0 : x0;
    B.u[3] = h ? own1 : x1;
    return B.v;
}

// ===========================================================================
// FULL PATH (requires ~98.6 MB workspace)
// ===========================================================================

// prep 1: x planes (fx, fvx, fx2) and W planes (fm, fw2=Wm^2+Wv, fv).
__global__ __launch_bounds__(256)
void prep_xw(const float* __restrict__ x, const float* __restrict__ vx,
             const float* __restrict__ Wm, const float* __restrict__ Wv,
             ushort_t* __restrict__ fx, ushort_t* __restrict__ fvx, ushort_t* __restrict__ fx2,
             ushort_t* __restrict__ fm, ushort_t* __restrict__ fw2, ushort_t* __restrict__ fv)
{
    const size_t g = (size_t)blockIdx.x * 256 + threadIdx.x;
    if (g < 524288) {                       // x side: 4M elts / 8
        const size_t o = g * 8;
        float4 a = *(const float4*)(x + o),  b = *(const float4*)(x + o + 4);
        float4 c = *(const float4*)(vx + o), d = *(const float4*)(vx + o + 4);
        *(uint4*)(fx  + o) = make_uint4(pk(a.x,a.y), pk(a.z,a.w), pk(b.x,b.y), pk(b.z,b.w));
        *(uint4*)(fvx + o) = make_uint4(pk(c.x,c.y), pk(c.z,c.w), pk(d.x,d.y), pk(d.z,d.w));
        *(uint4*)(fx2 + o) = make_uint4(pk(a.x*a.x,a.y*a.y), pk(a.z*a.z,a.w*a.w),
                                        pk(b.x*b.x,b.y*b.y), pk(b.z*b.z,b.w*b.w));
    } else {                                // W side: 1M elts / 8
        const size_t o = (g - 524288) * 8;
        float4 a = *(const float4*)(Wm + o), b = *(const float4*)(Wm + o + 4);
        float4 c = *(const float4*)(Wv + o), d = *(const float4*)(Wv + o + 4);
        *(uint4*)(fm  + o) = make_uint4(pk(a.x,a.y), pk(a.z,a.w), pk(b.x,b.y), pk(b.z,b.w));
        *(uint4*)(fv  + o) = make_uint4(pk(c.x,c.y), pk(c.z,c.w), pk(d.x,d.y), pk(d.z,d.w));
        *(uint4*)(fw2 + o) = make_uint4(pk(fmaf(a.x,a.x,c.x), fmaf(a.y,a.y,c.y)),
                                        pk(fmaf(a.z,a.z,c.z), fmaf(a.w,a.w,c.w)),
                                        pk(fmaf(b.x,b.x,d.x), fmaf(b.y,b.y,d.y)),
                                        pk(fmaf(b.z,b.z,d.z), fmaf(b.w,b.w,d.w)));
    }
}

// prep 2: K planes [bh][j][dh] (km,k2,kv) and transposed V planes [bh][dh][j].
__global__ __launch_bounds__(256)
void prep_kv(const float* __restrict__ K,  const float* __restrict__ VK,
             const float* __restrict__ Vv, const float* __restrict__ VV,
             ushort_t* __restrict__ kmP, ushort_t* __restrict__ k2P, ushort_t* __restrict__ kvP,
             ushort_t* __restrict__ vmT, ushort_t* __restrict__ wT,  ushort_t* __restrict__ vvT)
{
    __shared__ ushort_t Lm[64][68], Lw[64][68], Lv[64][68];
    const int tid = threadIdx.x;
    const int bh = blockIdx.x, jt = blockIdx.y;
    const int jr = tid >> 2, c0 = (tid & 3) * 16;
    const size_t gin = ((size_t)bh * NS + jt * 64 + jr) * NDH + c0;

    float kk[16], uu[16], vm[16], vv[16];
    #pragma unroll
    for (int q = 0; q < 4; ++q) {
        *(float4*)(kk + 4*q) = *(const float4*)(K  + gin + 4*q);
        *(float4*)(uu + 4*q) = *(const float4*)(VK + gin + 4*q);
        *(float4*)(vm + 4*q) = *(const float4*)(Vv + gin + 4*q);
        *(float4*)(vv + 4*q) = *(const float4*)(VV + gin + 4*q);
    }
    unsigned okm[8], ok2[8], okv[8];
    #pragma unroll
    for (int t = 0; t < 8; ++t) {
        okm[t] = pk(kk[2*t], kk[2*t+1]);
        ok2[t] = pk(fmaf(kk[2*t],kk[2*t],uu[2*t]), fmaf(kk[2*t+1],kk[2*t+1],uu[2*t+1]));
        okv[t] = pk(uu[2*t], uu[2*t+1]);
    }
    *(uint4*)(kmP + gin)     = make_uint4(okm[0],okm[1],okm[2],okm[3]);
    *(uint4*)(kmP + gin + 8) = make_uint4(okm[4],okm[5],okm[6],okm[7]);
    *(uint4*)(k2P + gin)     = make_uint4(ok2[0],ok2[1],ok2[2],ok2[3]);
    *(uint4*)(k2P + gin + 8) = make_uint4(ok2[4],ok2[5],ok2[6],ok2[7]);
    *(uint4*)(kvP + gin)     = make_uint4(okv[0],okv[1],okv[2],okv[3]);
    *(uint4*)(kvP + gin + 8) = make_uint4(okv[4],okv[5],okv[6],okv[7]);

    #pragma unroll
    for (int i = 0; i < 16; ++i) {
        Lm[jr][c0+i] = f2b(vm[i]);
        Lw[jr][c0+i] = f2b(fmaf(vm[i], vm[i], vv[i]));
        Lv[jr][c0+i] = f2b(vv[i]);
    }
    __syncthreads();
    const int dh = tid & 63, jj0 = (tid >> 6) * 16;
    unsigned om[8], ow[8], ov[8];
    #pragma unroll
    for (int t = 0; t < 8; ++t) {
        om[t] = ((unsigned)Lm[jj0+2*t][dh]) | (((unsigned)Lm[jj0+2*t+1][dh]) << 16);
        ow[t] = ((unsigned)Lw[jj0+2*t][dh]) | (((unsigned)Lw[jj0+2*t+1][dh]) << 16);
        ov[t] = ((unsigned)Lv[jj0+2*t][dh]) | (((unsigned)Lv[jj0+2*t+1][dh]) << 16);
    }
    const size_t got = ((size_t)bh * NDH + dh) * NS + jt * 64 + jj0;
    *(uint4*)(vmT + got)     = make_uint4(om[0],om[1],om[2],om[3]);
    *(uint4*)(vmT + got + 8) = make_uint4(om[4],om[5],om[6],om[7]);
    *(uint4*)(wT  + got)     = make_uint4(ow[0],ow[1],ow[2],ow[3]);
    *(uint4*)(wT  + got + 8) = make_uint4(ow[4],ow[5],ow[6],ow[7]);
    *(uint4*)(vvT + got)     = make_uint4(ov[0],ov[1],ov[2],ov[3]);
    *(uint4*)(vvT + got + 8) = make_uint4(ov[4],ov[5],ov[6],ov[7]);
}

// qproj from bf16 planes: pure load->MFMA. Output pre-scaled: qm*=2^-5, vq*=2^-10.
__global__ __launch_bounds__(256, 3)
void qproj_b(const ushort_t* __restrict__ fx, const ushort_t* __restrict__ fvx,
             const ushort_t* __restrict__ fx2,
             const ushort_t* __restrict__ fm, const ushort_t* __restrict__ fw2,
             const ushort_t* __restrict__ fv,
             ushort_t* __restrict__ qm_ws, ushort_t* __restrict__ vq_ws)
{
    const int tid  = threadIdx.x;
    const int w    = tid >> 6;
    const int lane = tid & 63;
    const int lh   = lane & 31;
    const int h    = lane >> 5;
    const int head = blockIdx.x;
    const int mb   = blockIdx.y;
    const int mrow = mb * 128 + w * 32 + lh;

    f16v aQ0 = zero16(), aQ1 = zero16(), aV0 = zero16(), aV1 = zero16();

    const ushort_t* xr  = fx  + (size_t)mrow * ND + 8*h;
    const ushort_t* vr  = fvx + (size_t)mrow * ND + 8*h;
    const ushort_t* x2r = fx2 + (size_t)mrow * ND + 8*h;
    const int n0 = head * 64 + lh, n1 = n0 + 32;
    const ushort_t* m0p = fm  + (size_t)n0 * ND + 8*h;
    const ushort_t* m1p = fm  + (size_t)n1 * ND + 8*h;
    const ushort_t* w0p = fw2 + (size_t)n0 * ND + 8*h;
    const ushort_t* w1p = fw2 + (size_t)n1 * ND + 8*h;
    const ushort_t* v0p = fv  + (size_t)n0 * ND + 8*h;
    const ushort_t* v1p = fv  + (size_t)n1 * ND + 8*h;

    for (int kc = 0; kc < 64; ++kc) {
        const int off = kc * 16;
        bf8 bx  = *(const bf8*)(xr  + off);
        bf8 bvx = *(const bf8*)(vr  + off);
        bf8 bx2 = *(const bf8*)(x2r + off);
        bf8 am0 = *(const bf8*)(m0p + off);
        bf8 aw0 = *(const bf8*)(w0p + off);
        bf8 av0 = *(const bf8*)(v0p + off);
        bf8 am1 = *(const bf8*)(m1p + off);
        bf8 aw1 = *(const bf8*)(w1p + off);
        bf8 av1 = *(const bf8*)(v1p + off);
        aQ0 = __builtin_amdgcn_mfma_f32_32x32x16_bf16(am0, bx,  aQ0, 0, 0, 0);
        aV0 = __builtin_amdgcn_mfma_f32_32x32x16_bf16(aw0, bvx, aV0, 0, 0, 0);
        aV0 = __builtin_amdgcn_mfma_f32_32x32x16_bf16(av0, bx2, aV0, 0, 0, 0);
        aQ1 = __builtin_amdgcn_mfma_f32_32x32x16_bf16(am1, bx,  aQ1, 0, 0, 0);
        aV1 = __builtin_amdgcn_mfma_f32_32x32x16_bf16(aw1, bvx, aV1, 0, 0, 0);
        aV1 = __builtin_amdgcn_mfma_f32_32x32x16_bf16(av1, bx2, aV1, 0, 0, 0);
    }

    const int b = mrow >> 10, srow = mrow & 1023;
    ushort_t* qp = qm_ws + (((size_t)(b * NH + head)) * NS + srow) * NDH;
    ushort_t* vp = vq_ws + (((size_t)(b * NH + head)) * NS + srow) * NDH;
    const float S1 = 0.03125f, S2 = 0.0009765625f;
    #pragma unroll
    for (int i = 0; i < 16; i += 2) {
        const int dh0 = (i & 3) + 8 * (i >> 2) + 4 * h;
        *(unsigned*)(qp + dh0)      = pk(aQ0[i]*S1, aQ0[i+1]*S1);
        *(unsigned*)(qp + 32 + dh0) = pk(aQ1[i]*S1, aQ1[i+1]*S1);
        *(unsigned*)(vp + dh0)      = pk(aV0[i]*S2, aV0[i+1]*S2);
        *(unsigned*)(vp + 32 + dh0) = pk(aV1[i]*S2, aV1[i+1]*S2);
    }
}

// Fused causal VDP attention from bf16 planes. 128 thr (2 waves x 32 rows),
// grid 64bh x 16rb. Pure load->MFMA inner loop, defer-max rescale (THR=8).
__global__ __launch_bounds__(128, 2)
void attn_b(const ushort_t* __restrict__ qm_ws, const ushort_t* __restrict__ vq_ws,
            const ushort_t* __restrict__ kmP, const ushort_t* __restrict__ k2P,
            const ushort_t* __restrict__ kvP,
            const ushort_t* __restrict__ vmT, const ushort_t* __restrict__ wT,
            const ushort_t* __restrict__ vvT,
            const float* __restrict__ x,
            float* __restrict__ out0, float* __restrict__ out1)
{
    __shared__ float lds[64][65];

    const int tid  = threadIdx.x;
    const int w    = tid >> 6;
    const int lane = tid & 63;
    const int lh   = lane & 31;
    const int h    = lane >> 5;
    const int lb   = (blockIdx.x & 7) * 128 + (blockIdx.x >> 3);  // XCD-chunked
    const int rb   = 15 - (lb & 15);                              // heavy-first
    const int bh   = lb >> 4;
    const int row0w = rb * 64 + w * 32;
    const int rg   = row0w + lh;
    const size_t baseJ = (size_t)bh * NS * NDH;
    const size_t baseT = (size_t)bh * NDH * NS;

    // persistent Q frags (pre-scaled): qm*2^-5, vq*2^-10, q2 = (qm*2^-5)^2
    bf8 fqm[4], fvq[4], fq2[4];
    {
        const ushort_t* qp = qm_ws + baseJ + (size_t)rg * NDH + 8*h;
        const ushort_t* vp = vq_ws + baseJ + (size_t)rg * NDH + 8*h;
        #pragma unroll
        for (int c = 0; c < 4; ++c) {
            fqm[c] = *(const bf8*)(qp + 16*c);
            fvq[c] = *(const bf8*)(vp + 16*c);
            U8 t; t.v = fqm[c];
            U8 r;
            #pragma unroll
            for (int k = 0; k < 4; ++k) {
                float q0 = b2f(t.s[2*k]), q1 = b2f(t.s[2*k+1]);
                r.u[k] = pk(q0*q0, q1*q1);
            }
            fq2[c] = r.v;
        }
    }

    f16v aN1[2], aN2w[2], aM2[2], aN3[2];
    #pragma unroll
    for (int dt = 0; dt < 2; ++dt) { aN1[dt]=zero16(); aN2w[dt]=zero16(); aM2[dt]=zero16(); aN3[dt]=zero16(); }
    float mrun = -INFINITY, Zrun = 0.f, S2run = 0.f;

    const int nsub = 2 * rb + w + 1;
    for (int st = 0; st < nsub; ++st) {
        const int j0 = st * 32;
        // ---- phase 1: scores (pure load->MFMA) ----
        f16v accA = zero16(), accU = zero16();
        #pragma unroll
        for (int c = 0; c < 4; ++c) {
            const size_t ko = baseJ + (size_t)(j0 + lh) * NDH + 16*c + 8*h;
            bf8 A0 = *(const bf8*)(kmP + ko);
            bf8 A1 = *(const bf8*)(k2P + ko);
            bf8 A2 = *(const bf8*)(kvP + ko);
            accA = __builtin_amdgcn_mfma_f32_32x32x16_bf16(A0, fqm[c], accA, 0, 0, 0);
            accU = __builtin_amdgcn_mfma_f32_32x32x16_bf16(A1, fvq[c], accU, 0, 0, 0);
            accU = __builtin_amdgcn_mfma_f32_32x32x16_bf16(A2, fq2[c], accU, 0, 0, 0);
        }
        if (st == nsub - 1) {                 // diagonal: mask j_loc > lh
            #pragma unroll
            for (int i = 0; i < 16; ++i) {
                const int jl = (i & 3) + 8 * (i >> 2) + 4 * h;
                if (jl > lh) accA[i] = -INFINITY;
            }
        }
        // ---- online softmax with defer-max (per-row state, r = lh) ----
        float mx = accA[0];
        #pragma unroll
        for (int i = 1; i < 16; ++i) mx = fmaxf(mx, accA[i]);
        mx = fmaxf(mx, __shfl_xor(mx, 32));
        if (!__all(mx <= mrun + 8.f)) {
            const float mnew = fmaxf(mrun, mx);
            const float s1 = __expf(mrun - mnew);
            const float s2 = s1 * s1, s3 = s2 * s1;
            Zrun *= s1; S2run *= s2;
            #pragma unroll
            for (int dt = 0; dt < 2; ++dt) { vscale(aN1[dt],s1); vscale(aN2w[dt],s2); vscale(aM2[dt],s2); vscale(aN3[dt],s3); }
            mrun = mnew;
        }
        float Zt = 0.f, St = 0.f;
        #pragma unroll
        for (int i = 0; i < 16; ++i) {
            const float e = __expf(accA[i] - mrun);
            accA[i] = e;                      // in place: accA now holds e
            Zt += e; St = fmaf(e * e, accU[i], St);
        }
        Zt += __shfl_xor(Zt, 32); St += __shfl_xor(St, 32);
        Zrun += Zt; S2run += St;

        // ---- phase 2: PV (coef packs per c2, V frags direct from planes) ----
        #pragma unroll
        for (int c2 = 0; c2 < 2; ++c2) {
            unsigned pE[4], pE2[4], pEU[4], pE3[4];
            #pragma unroll
            for (int k = 0; k < 4; ++k) {
                const int i0 = 8*c2 + 2*k;
                const float e0 = accA[i0], e1 = accA[i0+1];
                const float q0 = e0*e0, q1 = e1*e1;
                const float t0 = q0*accU[i0], t1 = q1*accU[i0+1];
                pE [k] = pk(e0, e1);
                pE2[k] = pk(q0, q1);
                pEU[k] = pk(t0, t1);
                pE3[k] = pk(t0*e0, t1*e1);
            }
            bf8 BE  = mkB(pE [0], pE [1], pE [2], pE [3], h);
            bf8 BE2 = mkB(pE2[0], pE2[1], pE2[2], pE2[3], h);
            bf8 BEU = mkB(pEU[0], pEU[1], pEU[2], pEU[3], h);
            bf8 BE3 = mkB(pE3[0], pE3[1], pE3[2], pE3[3], h);
            #pragma unroll
            for (int dt = 0; dt < 2; ++dt) {
                const size_t vo = baseT + (size_t)(32*dt + lh) * NS + j0 + 16*c2 + 8*h;
                bf8 Am = *(const bf8*)(vmT + vo);
                bf8 Aw = *(const bf8*)(wT  + vo);
                bf8 Av = *(const bf8*)(vvT + vo);
                aN1[dt]  = __builtin_amdgcn_mfma_f32_32x32x16_bf16(Am, BE,  aN1[dt],  0, 0, 0);
                aN2w[dt] = __builtin_amdgcn_mfma_f32_32x32x16_bf16(Aw, BE2, aN2w[dt], 0, 0, 0);
                aM2[dt]  = __builtin_amdgcn_mfma_f32_32x32x16_bf16(Aw, BEU, aM2[dt],  0, 0, 0);
                aM2[dt]  = __builtin_amdgcn_mfma_f32_32x32x16_bf16(Av, BE2, aM2[dt],  0, 0, 0);
                aN3[dt]  = __builtin_amdgcn_mfma_f32_32x32x16_bf16(Aw, BE3, aN3[dt],  0, 0, 0);
            }
        }
    }

    // ---- epilogue ----
    const float rZ  = 1.f / Zrun;
    const float rZ2 = rZ * rZ;
    const float sS  = S2run * rZ2;
    const int b = bh >> 4, head = bh & 15;

    #pragma unroll
    for (int dt = 0; dt < 2; ++dt)
        #pragma unroll
        for (int i = 0; i < 16; ++i) {
            const int col = 32*dt + (i & 3) + 8*(i >> 2) + 4*h;
            lds[w*32 + lh][col] = aN1[dt][i] * rZ;
        }
    __syncthreads();
    {
        const int row = tid >> 1, half = (tid & 1) * 32;
        const size_t o = ((size_t)b * NS + rb*64 + row) * ND + head * NDH + half;
        #pragma unroll
        for (int q4 = 0; q4 < 32; q4 += 4) {
            float4 t = make_float4(lds[row][half+q4], lds[row][half+q4+1],
                                   lds[row][half+q4+2], lds[row][half+q4+3]);
            float4 xi = *(const float4*)(x + o + q4);
            *(float4*)(out0 + o + q4) = make_float4(t.x+xi.x, t.y+xi.y, t.z+xi.z, t.w+xi.w);
        }
    }
    __syncthreads();
    #pragma unroll
    for (int dt = 0; dt < 2; ++dt)
        #pragma unroll
        for (int i = 0; i < 16; ++i) {
            const int col = 32*dt + (i & 3) + 8*(i >> 2) + 4*h;
            lds[w*32 + lh][col] = rZ2 * fmaf(sS, aN2w[dt][i], aM2[dt][i]) - 2.f*rZ2*rZ*aN3[dt][i];
        }
    __syncthreads();
    {
        const int row = tid >> 1, half = (tid & 1) * 32;
        const size_t o = ((size_t)b * NS + rb*64 + row) * ND + head * NDH + half;
        #pragma unroll
        for (int q4 = 0; q4 < 32; q4 += 4) {
            float4 t = make_float4(lds[row][half+q4], lds[row][half+q4+1],
                                   lds[row][half+q4+2], lds[row][half+q4+3]);
            *(float4*)(out1 + o + q4) = t;
        }
    }
}

// ===========================================================================
// FALLBACK PATH (round-4 kernels, ~16 MB ws) — used if ws_size is too small.
// ===========================================================================
__global__ __launch_bounds__(256, 3)
void qproj_fb(const float* __restrict__ x, const float* __restrict__ vx,
              const float* __restrict__ Wm, const float* __restrict__ Wv,
              ushort_t* __restrict__ qm_ws, ushort_t* __restrict__ vq_ws)
{
    const int tid  = threadIdx.x;
    const int w    = tid >> 6;
    const int lane = tid & 63;
    const int lh   = lane & 31;
    const int h    = lane >> 5;
    const int head = blockIdx.x;
    const int mb   = blockIdx.y;
    const int mrow = mb * 128 + w * 32 + lh;

    f16v aQ0 = zero16(), aQ1 = zero16(), aV0 = zero16(), aV1 = zero16();

    const float* xr = x  + (size_t)mrow * ND;
    const float* vr = vx + (size_t)mrow * ND;
    const float* w0 = Wm + (size_t)(head*64 +      lh) * ND;
    const float* w1 = Wm + (size_t)(head*64 + 32 + lh) * ND;
    const float* v0 = Wv + (size_t)(head*64 +      lh) * ND;
    const float* v1 = Wv + (size_t)(head*64 + 32 + lh) * ND;

    for (int kc = 0; kc < 64; ++kc) {
        const int ko = kc * 16 + 8 * h;
        float4 xa = *(const float4*)(xr + ko); float4 xb = *(const float4*)(xr + ko + 4);
        float4 va = *(const float4*)(vr + ko); float4 vb = *(const float4*)(vr + ko + 4);
        U8 fx_, fvx_, fx2_;
        fx_.u[0]  = pk(xa.x, xa.y); fx_.u[1]  = pk(xa.z, xa.w);
        fx_.u[2]  = pk(xb.x, xb.y); fx_.u[3]  = pk(xb.z, xb.w);
        fvx_.u[0] = pk(va.x, va.y); fvx_.u[1] = pk(va.z, va.w);
        fvx_.u[2] = pk(vb.x, vb.y); fvx_.u[3] = pk(vb.z, vb.w);
        fx2_.u[0] = pk(xa.x*xa.x, xa.y*xa.y); fx2_.u[1] = pk(xa.z*xa.z, xa.w*xa.w);
        fx2_.u[2] = pk(xb.x*xb.x, xb.y*xb.y); fx2_.u[3] = pk(xb.z*xb.z, xb.w*xb.w);
        {
            float4 ma = *(const float4*)(w0 + ko); float4 mb4 = *(const float4*)(w0 + ko + 4);
            float4 wa = *(const float4*)(v0 + ko); float4 wb  = *(const float4*)(v0 + ko + 4);
            U8 fm_, fw2_, fv_;
            fm_.u[0]  = pk(ma.x, ma.y);   fm_.u[1] = pk(ma.z, ma.w);
            fm_.u[2]  = pk(mb4.x, mb4.y); fm_.u[3] = pk(mb4.z, mb4.w);
            fv_.u[0]  = pk(wa.x, wa.y);   fv_.u[1] = pk(wa.z, wa.w);
            fv_.u[2]  = pk(wb.x, wb.y);   fv_.u[3] = pk(wb.z, wb.w);
            fw2_.u[0] = pk(fmaf(ma.x,ma.x,wa.x),  fmaf(ma.y,ma.y,wa.y));
            fw2_.u[1] = pk(fmaf(ma.z,ma.z,wa.z),  fmaf(ma.w,ma.w,wa.w));
            fw2_.u[2] = pk(fmaf(mb4.x,mb4.x,wb.x), fmaf(mb4.y,mb4.y,wb.y));
            fw2_.u[3] = pk(fmaf(mb4.z,mb4.z,wb.z), fmaf(mb4.w,mb4.w,wb.w));
            aQ0 = __builtin_amdgcn_mfma_f32_32x32x16_bf16(fm_.v,  fx_.v,  aQ0, 0, 0, 0);
            aV0 = __builtin_amdgcn_mfma_f32_32x32x16_bf16(fw2_.v, fvx_.v, aV0, 0, 0, 0);
            aV0 = __builtin_amdgcn_mfma_f32_32x32x16_bf16(fv_.v,  fx2_.v, aV0, 0, 0, 0);
        }
        {
            float4 ma = *(const float4*)(w1 + ko); float4 mb4 = *(const float4*)(w1 + ko + 4);
            float4 wa = *(const float4*)(v1 + ko); float4 wb  = *(const float4*)(v1 + ko + 4);
            U8 fm_, fw2_, fv_;
            fm_.u[0]  = pk(ma.x, ma.y);   fm_.u[1] = pk(ma.z, ma.w);
            fm_.u[2]  = pk(mb4.x, mb4.y); fm_.u[3] = pk(mb4.z, mb4.w);
            fv_.u[0]  = pk(wa.x, wa.y);   fv_.u[1] = pk(wa.z, wa.w);
            fv_.u[2]  = pk(wb.x, wb.y);   fv_.u[3] = pk(wb.z, wb.w);
            fw2_.u[0] = pk(fmaf(ma.x,ma.x,wa.x),  fmaf(ma.y,ma.y,wa.y));
            fw2_.u[1] = pk(fmaf(ma.z,ma.z,wa.z),  fmaf(ma.w,ma.w,wa.w));
            fw2_.u[2] = pk(fmaf(mb4.x,mb4.x,wb.x), fmaf(mb4.y,mb4.y,wb.y));
            fw2_.u[3] = pk(fmaf(mb4.z,mb4.z,wb.z), fmaf(mb4.w,mb4.w,wb.w));
            aQ1 = __builtin_amdgcn_mfma_f32_32x32x16_bf16(fm_.v,  fx_.v,  aQ1, 0, 0, 0);
            aV1 = __builtin_amdgcn_mfma_f32_32x32x16_bf16(fw2_.v, fvx_.v, aV1, 0, 0, 0);
            aV1 = __builtin_amdgcn_mfma_f32_32x32x16_bf16(fv_.v,  fx2_.v, aV1, 0, 0, 0);
        }
    }
    const int b = mrow >> 10, srow = mrow & 1023;
    ushort_t* qp = qm_ws + (((size_t)(b * NH + head)) * NS + srow) * NDH;
    ushort_t* vp = vq_ws + (((size_t)(b * NH + head)) * NS + srow) * NDH;
    #pragma unroll
    for (int i = 0; i < 16; i += 2) {
        const int dh0 = (i & 3) + 8 * (i >> 2) + 4 * h;
        *(unsigned*)(qp + dh0)      = pk(aQ0[i], aQ0[i+1]);
        *(unsigned*)(qp + 32 + dh0) = pk(aQ1[i], aQ1[i+1]);
        *(unsigned*)(vp + dh0)      = pk(aV0[i], aV0[i+1]);
        *(unsigned*)(vp + 32 + dh0) = pk(aV1[i], aV1[i+1]);
    }
}

__global__ __launch_bounds__(256, 2)
void attn_fb(const ushort_t* __restrict__ qm_ws, const ushort_t* __restrict__ vq_ws,
             const float* __restrict__ K,  const float* __restrict__ VK,
             const float* __restrict__ Vv, const float* __restrict__ VV,
             const float* __restrict__ x,
             float* __restrict__ out0, float* __restrict__ out1)
{
    __shared__ float lds[128][65];
    const int tid  = threadIdx.x;
    const int w    = tid >> 6;
    const int lane = tid & 63;
    const int lh   = lane & 31;
    const int h    = lane >> 5;
    const int blk  = blockIdx.x;
    const int rb   = 7 - (blk & 7);
    const int bh   = blk >> 3;
    const int row0 = rb * 128 + w * 32;
    const int rg   = row0 + lh;
    const size_t base = (size_t)bh * NS * NDH;

    bf8 fqm[4], fvq[4], fq2[4];
    {
        const ushort_t* qp = qm_ws + base + (size_t)rg * NDH;
        const ushort_t* vp = vq_ws + base + (size_t)rg * NDH;
        #pragma unroll
        for (int c = 0; c < 4; ++c) {
            fqm[c] = *(const bf8*)(qp + 16*c + 8*h);
            fvq[c] = *(const bf8*)(vp + 16*c + 8*h);
            U8 t; t.v = fqm[c];
            U8 r;
            #pragma unroll
            for (int k = 0; k < 4; ++k) {
                float q0 = b2f(t.s[2*k]), q1 = b2f(t.s[2*k+1]);
                r.u[k] = pk(q0*q0, q1*q1);
            }
            fq2[c] = r.v;
        }
    }
    f16v aN1[2], aN2w[2], aM2[2], aN3[2];
    #pragma unroll
    for (int dt = 0; dt < 2; ++dt) { aN1[dt]=zero16(); aN2w[dt]=zero16(); aM2[dt]=zero16(); aN3[dt]=zero16(); }
    float mrun = -INFINITY, Zrun = 0.f, S2run = 0.f;

    const int nsub = 4 * rb + w + 1;
    for (int st = 0; st < nsub; ++st) {
        const int j0 = st * 32;
        f16v accA = zero16(), accU = zero16();
        #pragma unroll
        for (int c = 0; c < 4; ++c) {
            const float* kp = K  + base + (size_t)(j0 + lh) * NDH + 16*c + 8*h;
            const float* up = VK + base + (size_t)(j0 + lh) * NDH + 16*c + 8*h;
            float4 k0 = *(const float4*)kp, k1 = *(const float4*)(kp + 4);
            float4 u0 = *(const float4*)up, u1 = *(const float4*)(up + 4);
            U8 fkm, fk2, fkv;
            fkm.u[0] = pk(k0.x, k0.y); fkm.u[1] = pk(k0.z, k0.w);
            fkm.u[2] = pk(k1.x, k1.y); fkm.u[3] = pk(k1.z, k1.w);
            fkv.u[0] = pk(u0.x, u0.y); fkv.u[1] = pk(u0.z, u0.w);
            fkv.u[2] = pk(u1.x, u1.y); fkv.u[3] = pk(u1.z, u1.w);
            fk2.u[0] = pk(fmaf(k0.x,k0.x,u0.x), fmaf(k0.y,k0.y,u0.y));
            fk2.u[1] = pk(fmaf(k0.z,k0.z,u0.z), fmaf(k0.w,k0.w,u0.w));
            fk2.u[2] = pk(fmaf(k1.x,k1.x,u1.x), fmaf(k1.y,k1.y,u1.y));
            fk2.u[3] = pk(fmaf(k1.z,k1.z,u1.z), fmaf(k1.w,k1.w,u1.w));
            accA = __builtin_amdgcn_mfma_f32_32x32x16_bf16(fkm.v, fqm[c], accA, 0, 0, 0);
            accU = __builtin_amdgcn_mfma_f32_32x32x16_bf16(fk2.v, fvq[c], accU, 0, 0, 0);
            accU = __builtin_amdgcn_mfma_f32_32x32x16_bf16(fkv.v, fq2[c], accU, 0, 0, 0);
        }
        float a[16], u[16];
        #pragma unroll
        for (int i = 0; i < 16; ++i) { a[i] = accA[i] * 0.03125f; u[i] = accU[i] * 0.0009765625f; }
        if (st == nsub - 1) {
            #pragma unroll
            for (int i = 0; i < 16; ++i) {
                const int jl = (i & 3) + 8 * (i >> 2) + 4 * h;
                if (jl > lh) a[i] = -INFINITY;
            }
        }
        float mx = a[0];
        #pragma unroll
        for (int i = 1; i < 16; ++i) mx = fmaxf(mx, a[i]);
        mx = fmaxf(mx, __shfl_xor(mx, 32));
        const float mnew = fmaxf(mrun, mx);
        const float s1 = __expf(mrun - mnew);
        float ex[16];
        float Zt = 0.f, St = 0.f;
        #pragma unroll
        for (int i = 0; i < 16; ++i) {
            float ee = __expf(a[i] - mnew);
            ex[i] = ee; Zt += ee; St = fmaf(ee*ee, u[i], St);
        }
        Zt += __shfl_xor(Zt, 32); St += __shfl_xor(St, 32);
        const float s2 = s1*s1, s3 = s2*s1;
        Zrun = fmaf(Zrun, s1, Zt); S2run = fmaf(S2run, s2, St); mrun = mnew;
        #pragma unroll
        for (int dt = 0; dt < 2; ++dt) { vscale(aN1[dt],s1); vscale(aN2w[dt],s2); vscale(aM2[dt],s2); vscale(aN3[dt],s3); }
        unsigned PE[8], PE2[8], PEU[8], PE3[8];
        #pragma unroll
        for (int k = 0; k < 8; ++k) {
            float e0 = ex[2*k], e1 = ex[2*k+1];
            float q0 = e0*e0, q1 = e1*e1;
            float t0 = q0*u[2*k], t1 = q1*u[2*k+1];
            PE[k] = pk(e0, e1); PE2[k] = pk(q0, q1); PEU[k] = pk(t0, t1); PE3[k] = pk(t0*e0, t1*e1);
        }
        #pragma unroll
        for (int c2 = 0; c2 < 2; ++c2) {
            bf8 BE  = mkB(PE [4*c2], PE [4*c2+1], PE [4*c2+2], PE [4*c2+3], h);
            bf8 BE2 = mkB(PE2[4*c2], PE2[4*c2+1], PE2[4*c2+2], PE2[4*c2+3], h);
            bf8 BEU = mkB(PEU[4*c2], PEU[4*c2+1], PEU[4*c2+2], PEU[4*c2+3], h);
            bf8 BE3 = mkB(PE3[4*c2], PE3[4*c2+1], PE3[4*c2+2], PE3[4*c2+3], h);
            #pragma unroll
            for (int dt = 0; dt < 2; ++dt) {
                const float* vmb = Vv + base + (size_t)(j0 + 16*c2 + 8*h) * NDH + 32*dt + lh;
                const float* vvb = VV + base + (size_t)(j0 + 16*c2 + 8*h) * NDH + 32*dt + lh;
                float vm[8], vv[8];
                #pragma unroll
                for (int e = 0; e < 8; ++e) { vm[e] = vmb[e * NDH]; vv[e] = vvb[e * NDH]; }
                U8 fvm, fw, fvv;
                #pragma unroll
                for (int k = 0; k < 4; ++k) {
                    float w0f = fmaf(vm[2*k],   vm[2*k],   vv[2*k]);
                    float w1f = fmaf(vm[2*k+1], vm[2*k+1], vv[2*k+1]);
                    fvm.u[k] = pk(vm[2*k], vm[2*k+1]);
                    fw.u[k]  = pk(w0f, w1f);
                    fvv.u[k] = pk(vv[2*k], vv[2*k+1]);
                }
                aN1[dt]  = __builtin_amdgcn_mfma_f32_32x32x16_bf16(fvm.v, BE,  aN1[dt],  0, 0, 0);
                aN2w[dt] = __builtin_amdgcn_mfma_f32_32x32x16_bf16(fw.v,  BE2, aN2w[dt], 0, 0, 0);
                aM2[dt]  = __builtin_amdgcn_mfma_f32_32x32x16_bf16(fw.v,  BEU, aM2[dt],  0, 0, 0);
                aM2[dt]  = __builtin_amdgcn_mfma_f32_32x32x16_bf16(fvv.v, BE2, aM2[dt],  0, 0, 0);
                aN3[dt]  = __builtin_amdgcn_mfma_f32_32x32x16_bf16(fw.v,  BE3, aN3[dt],  0, 0, 0);
            }
        }
    }
    const float rZ  = 1.f / Zrun;
    const float rZ2 = rZ * rZ;
    const float sS  = S2run * rZ2;
    const int b = bh >> 4, head = bh & 15;
    #pragma unroll
    for (int dt = 0; dt < 2; ++dt)
        #pragma unroll
        for (int i = 0; i < 16; ++i) {
            const int col = 32*dt + (i & 3) + 8*(i >> 2) + 4*h;
            lds[w*32 + lh][col] = aN1[dt][i] * rZ;
        }
    __syncthreads();
    {
        const int row = tid >> 1, half = (tid & 1) * 32;
        const size_t o = ((size_t)b * NS + rb*128 + row) * ND + head * NDH + half;
        #pragma unroll
        for (int q4 = 0; q4 < 32; q4 += 4) {
            float4 t = make_float4(lds[row][half+q4], lds[row][half+q4+1],
                                   lds[row][half+q4+2], lds[row][half+q4+3]);
            float4 xi = *(const float4*)(x + o + q4);
            *(float4*)(out0 + o + q4) = make_float4(t.x+xi.x, t.y+xi.y, t.z+xi.z, t.w+xi.w);
        }
    }
    __syncthreads();
    #pragma unroll
    for (int dt = 0; dt < 2; ++dt)
        #pragma unroll
        for (int i = 0; i < 16; ++i) {
            const int col = 32*dt + (i & 3) + 8*(i >> 2) + 4*h;
            lds[w*32 + lh][col] = rZ2 * fmaf(sS, aN2w[dt][i], aM2[dt][i]) - 2.f*rZ2*rZ*aN3[dt][i];
        }
    __syncthreads();
    {
        const int row = tid >> 1, half = (tid & 1) * 32;
        const size_t o = ((size_t)b * NS + rb*128 + row) * ND + head * NDH + half;
        #pragma unroll
        for (int q4 = 0; q4 < 32; q4 += 4) {
            float4 t = make_float4(lds[row][half+q4], lds[row][half+q4+1],
                                   lds[row][half+q4+2], lds[row][half+q4+3]);
            *(float4*)(out1 + o + q4) = t;
        }
    }
}

extern "C" void kernel_launch(void* const* d_in, const int* in_sizes, int n_in,
                              void* d_out, int out_size, void* d_ws, size_t ws_size,
                              hipStream_t stream)
{
    (void)in_sizes; (void)n_in; (void)out_size;
    const float* x  = (const float*)d_in[0];
    const float* vx = (const float*)d_in[1];
    const float* K  = (const float*)d_in[2];
    const float* VK = (const float*)d_in[3];
    const float* Vv = (const float*)d_in[4];
    const float* VV = (const float*)d_in[5];
    const float* Wm = (const float*)d_in[6];
    const float* Wv = (const float*)d_in[7];

    float* out0 = (float*)d_out;
    float* out1 = out0 + (size_t)NB * NS * ND;

    const size_t M4 = 4194304, M1 = 1048576;
    const size_t need = (11 * M4 + 3 * M1) * 2;   // ~98.6 MB

    ushort_t* qm = (ushort_t*)d_ws;
    ushort_t* vq = qm + M4;

    if (ws_size >= need) {
        ushort_t* kmP = vq  + M4;
        ushort_t* k2P = kmP + M4;
        ushort_t* kvP = k2P + M4;
        ushort_t* vmT = kvP + M4;
        ushort_t* wT  = vmT + M4;
        ushort_t* vvT = wT  + M4;
        ushort_t* fx  = vvT + M4;
        ushort_t* fvx = fx  + M4;
        ushort_t* fx2 = fvx + M4;
        ushort_t* fm  = fx2 + M4;
        ushort_t* fw2 = fm  + M1;
        ushort_t* fv  = fw2 + M1;

        prep_xw<<<2560, 256, 0, stream>>>(x, vx, Wm, Wv, fx, fvx, fx2, fm, fw2, fv);
        prep_kv<<<dim3(64, 16), 256, 0, stream>>>(K, VK, Vv, VV, kmP, k2P, kvP, vmT, wT, vvT);
        qproj_b<<<dim3(NH, 32), 256, 0, stream>>>(fx, fvx, fx2, fm, fw2, fv, qm, vq);
        attn_b<<<1024, 128, 0, stream>>>(qm, vq, kmP, k2P, kvP, vmT, wT, vvT, x, out0, out1);
    } else {
        qproj_fb<<<dim3(NH, 32), 256, 0, stream>>>(x, vx, Wm, Wv, qm, vq);
        attn_fb<<<64 * 8, 256, 0, stream>>>(qm, vq, K, VK, Vv, VV, x, out0, out1);
    }
}

// Round 6
// 240.609 us; speedup vs baseline: 10.0106x; 1.5548x over previous
//
#include <hip/hip_runtime.h>
#include <hip/hip_bf16.h>
#include <math.h>

#define NB 4
#define NS 1024
#define ND 1024
#define NH 16
#define NDH 64

typedef float f16v __attribute__((ext_vector_type(16)));
typedef short bf8 __attribute__((ext_vector_type(8)));
typedef unsigned short ushort_t;

union U8 { bf8 v; unsigned u[4]; unsigned short s[8]; };

__device__ __forceinline__ unsigned pk(float lo, float hi) {
    __hip_bfloat162 h2 = __float22bfloat162_rn(make_float2(lo, hi));
    return *reinterpret_cast<unsigned*>(&h2);
}
__device__ __forceinline__ unsigned short f2b(float f) {
    unsigned u = __float_as_uint(f);
    unsigned r = (u + 0x7fffu + ((u >> 16) & 1u)) >> 16;   // RNE
    return (unsigned short)r;
}
__device__ __forceinline__ float b2f(unsigned short h) {
    return __uint_as_float(((unsigned)h) << 16);
}
__device__ __forceinline__ f16v zero16() {
    f16v z;
    #pragma unroll
    for (int i = 0; i < 16; ++i) z[i] = 0.f;
    return z;
}
__device__ __forceinline__ void vscale(f16v& v, float s) {
    #pragma unroll
    for (int i = 0; i < 16; ++i) v[i] *= s;
}

// Build PV B-frag (coef[j, r], K=16 chunk) from packed pairs p0..p3.
__device__ __forceinline__ bf8 mkB(unsigned p0, unsigned p1, unsigned p2, unsigned p3, int h) {
    unsigned own0 = h ? p2 : p0;
    unsigned own1 = h ? p3 : p1;
    unsigned ct0  = h ? p0 : p2;
    unsigned ct1  = h ? p1 : p3;
    unsigned x0 = (unsigned)__shfl_xor((int)ct0, 32);
    unsigned x1 = (unsigned)__shfl_xor((int)ct1, 32);
    U8 B;
    B.u[0] = h ? x0 : own0;
    B.u[1] = h ? x1 : own1;
    B.u[2] = h ? own0 : x0;
    B.u[3] = h ? own1 : x1;
    return B.v;
}

// ===========================================================================
// FULL PATH — all inter-kernel tensors in MFMA FRAGMENT ORDER:
//   every hot-loop load is  base + lane*16  (coalesced 1KB/wave).
//
// K planes  [bh][s][c][lane][8]:      elem (j,dh): s=j>>5, c=dh>>4,
//                                     l=(j&31)+32*((dh>>3)&1), e=dh&7
// V planes  [bh][s][dt*2+c2][lane][8]: elem (j,dh): s=j>>5, dt=dh>>5,
//                                     c2=(j>>4)&1, l=(dh&31)+32*((j>>3)&1), e=j&7
// x planes  [mt][kc][lane][8]:        elem (row,k): mt=row>>5, kc=k>>4,
//                                     l=(row&31)+32*((k>>3)&1), e=k&7
// W planes  [nt][kc][lane][8]:        same formula on (wrow,k)
// qm/vq     [bh][rt][c][lane][8]:     elem (r,dh) like K planes
// ===========================================================================

// prep 1: x planes (fx, fvx, fx2) and W planes (fm, fw2=Wm^2+Wv, fv), frag order.
__global__ __launch_bounds__(256)
void prep_xw(const float* __restrict__ x, const float* __restrict__ vx,
             const float* __restrict__ Wm, const float* __restrict__ Wv,
             ushort_t* __restrict__ fx, ushort_t* __restrict__ fvx, ushort_t* __restrict__ fx2,
             ushort_t* __restrict__ fm, ushort_t* __restrict__ fw2, ushort_t* __restrict__ fv)
{
    const size_t g = (size_t)blockIdx.x * 256 + threadIdx.x;
    if (g < 524288) {                       // x side: 4M elems / 8
        const size_t g0 = g * 8;
        const int row = (int)(g0 >> 10), k0 = (int)(g0 & 1023);
        const size_t fo = ((size_t)(row >> 5) * 64 + (k0 >> 4)) * 512
                        + ((row & 31) + 32 * ((k0 >> 3) & 1)) * 8;
        float a[8], c[8];
        *(float4*)(a)   = *(const float4*)(x + g0);  *(float4*)(a+4) = *(const float4*)(x + g0 + 4);
        *(float4*)(c)   = *(const float4*)(vx + g0); *(float4*)(c+4) = *(const float4*)(vx + g0 + 4);
        *(uint4*)(fx  + fo) = make_uint4(pk(a[0],a[1]), pk(a[2],a[3]), pk(a[4],a[5]), pk(a[6],a[7]));
        *(uint4*)(fvx + fo) = make_uint4(pk(c[0],c[1]), pk(c[2],c[3]), pk(c[4],c[5]), pk(c[6],c[7]));
        *(uint4*)(fx2 + fo) = make_uint4(pk(a[0]*a[0],a[1]*a[1]), pk(a[2]*a[2],a[3]*a[3]),
                                         pk(a[4]*a[4],a[5]*a[5]), pk(a[6]*a[6],a[7]*a[7]));
    } else {                                // W side: 1M elems / 8
        const size_t g0 = (g - 524288) * 8;
        const int row = (int)(g0 >> 10), k0 = (int)(g0 & 1023);
        const size_t fo = ((size_t)(row >> 5) * 64 + (k0 >> 4)) * 512
                        + ((row & 31) + 32 * ((k0 >> 3) & 1)) * 8;
        float a[8], c[8];
        *(float4*)(a)   = *(const float4*)(Wm + g0); *(float4*)(a+4) = *(const float4*)(Wm + g0 + 4);
        *(float4*)(c)   = *(const float4*)(Wv + g0); *(float4*)(c+4) = *(const float4*)(Wv + g0 + 4);
        *(uint4*)(fm  + fo) = make_uint4(pk(a[0],a[1]), pk(a[2],a[3]), pk(a[4],a[5]), pk(a[6],a[7]));
        *(uint4*)(fv  + fo) = make_uint4(pk(c[0],c[1]), pk(c[2],c[3]), pk(c[4],c[5]), pk(c[6],c[7]));
        *(uint4*)(fw2 + fo) = make_uint4(pk(fmaf(a[0],a[0],c[0]), fmaf(a[1],a[1],c[1])),
                                         pk(fmaf(a[2],a[2],c[2]), fmaf(a[3],a[3],c[3])),
                                         pk(fmaf(a[4],a[4],c[4]), fmaf(a[5],a[5],c[5])),
                                         pk(fmaf(a[6],a[6],c[6]), fmaf(a[7],a[7],c[7])));
    }
}

// prep 2: K planes (km,k2,kv) + V planes (vm,w,vv), frag order. Block = (bh, s).
__global__ __launch_bounds__(256)
void prep_kv(const float* __restrict__ K,  const float* __restrict__ VK,
             const float* __restrict__ Vv, const float* __restrict__ VV,
             ushort_t* __restrict__ kmF, ushort_t* __restrict__ k2F, ushort_t* __restrict__ kvF,
             ushort_t* __restrict__ vmF, ushort_t* __restrict__ wF,  ushort_t* __restrict__ vvF)
{
    __shared__ ushort_t Lm[2048], Lw[2048], Lv[2048];
    const int tid = threadIdx.x;
    const int bh = blockIdx.x, s = blockIdx.y;
    const int jp  = tid >> 3;               // 0..31 (j within subtile)
    const int dh0 = (tid & 7) * 8;
    const size_t gin = ((size_t)bh * NS + s * 32 + jp) * NDH + dh0;
    const size_t sbase = ((size_t)bh * 32 + s) * 2048;

    float kk[8], uu[8], vm[8], vv[8];
    *(float4*)(kk)   = *(const float4*)(K  + gin); *(float4*)(kk+4) = *(const float4*)(K  + gin + 4);
    *(float4*)(uu)   = *(const float4*)(VK + gin); *(float4*)(uu+4) = *(const float4*)(VK + gin + 4);
    *(float4*)(vm)   = *(const float4*)(Vv + gin); *(float4*)(vm+4) = *(const float4*)(Vv + gin + 4);
    *(float4*)(vv)   = *(const float4*)(VV + gin); *(float4*)(vv+4) = *(const float4*)(VV + gin + 4);

    // ---- K side: contiguous 16B frag-order stores ----
    const size_t kout = sbase + (size_t)((tid & 7) >> 1) * 512
                      + (jp + 32 * ((tid & 7) & 1)) * 8;
    unsigned o0[4], o1[4], o2[4];
    #pragma unroll
    for (int t = 0; t < 4; ++t) {
        o0[t] = pk(kk[2*t], kk[2*t+1]);
        o1[t] = pk(fmaf(kk[2*t],kk[2*t],uu[2*t]), fmaf(kk[2*t+1],kk[2*t+1],uu[2*t+1]));
        o2[t] = pk(uu[2*t], uu[2*t+1]);
    }
    *(uint4*)(kmF + kout) = make_uint4(o0[0],o0[1],o0[2],o0[3]);
    *(uint4*)(k2F + kout) = make_uint4(o1[0],o1[1],o1[2],o1[3]);
    *(uint4*)(kvF + kout) = make_uint4(o2[0],o2[1],o2[2],o2[3]);

    // ---- V side: scatter to LDS, then linear copy out ----
    #pragma unroll
    for (int e = 0; e < 8; ++e) {
        const int dh = dh0 + e;
        const int idx = ((dh >> 5) * 2 + (jp >> 4)) * 512
                      + ((dh & 31) + 32 * ((jp >> 3) & 1)) * 8 + (jp & 7);
        Lm[idx] = f2b(vm[e]);
        Lw[idx] = f2b(fmaf(vm[e], vm[e], vv[e]));
        Lv[idx] = f2b(vv[e]);
    }
    __syncthreads();
    const size_t vout = sbase + (size_t)tid * 8;
    *(uint4*)(vmF + vout) = *(const uint4*)(Lm + tid * 8);
    *(uint4*)(wF  + vout) = *(const uint4*)(Lw + tid * 8);
    *(uint4*)(vvF + vout) = *(const uint4*)(Lv + tid * 8);
}

// qproj from frag-order planes; writes qm/vq in attn's Q-frag order, pre-scaled.
__global__ __launch_bounds__(256, 3)
void qproj_b(const ushort_t* __restrict__ fxF, const ushort_t* __restrict__ fvxF,
             const ushort_t* __restrict__ fx2F,
             const ushort_t* __restrict__ fmF, const ushort_t* __restrict__ fw2F,
             const ushort_t* __restrict__ fvF,
             ushort_t* __restrict__ qmF, ushort_t* __restrict__ vqF)
{
    const int tid  = threadIdx.x;
    const int w    = tid >> 6;
    const int lane = tid & 63;
    const int lh   = lane & 31;
    const int h    = lane >> 5;
    const int head = blockIdx.x;
    const int mb   = blockIdx.y;
    const int mt   = mb * 4 + w;            // 32-row m-tile (0..127)
    const int nt0  = head * 2, nt1 = nt0 + 1;

    f16v aQ0 = zero16(), aQ1 = zero16(), aV0 = zero16(), aV1 = zero16();

    const ushort_t* bx  = fxF  + (size_t)mt * 64 * 512 + lane * 8;
    const ushort_t* bvx = fvxF + (size_t)mt * 64 * 512 + lane * 8;
    const ushort_t* bx2 = fx2F + (size_t)mt * 64 * 512 + lane * 8;
    const ushort_t* am0 = fmF  + (size_t)nt0 * 64 * 512 + lane * 8;
    const ushort_t* aw0 = fw2F + (size_t)nt0 * 64 * 512 + lane * 8;
    const ushort_t* av0 = fvF  + (size_t)nt0 * 64 * 512 + lane * 8;
    const ushort_t* am1 = fmF  + (size_t)nt1 * 64 * 512 + lane * 8;
    const ushort_t* aw1 = fw2F + (size_t)nt1 * 64 * 512 + lane * 8;
    const ushort_t* av1 = fvF  + (size_t)nt1 * 64 * 512 + lane * 8;

    for (int kc = 0; kc < 64; ++kc) {
        const int off = kc * 512;
        bf8 vb  = *(const bf8*)(bx  + off);
        bf8 vbv = *(const bf8*)(bvx + off);
        bf8 vb2 = *(const bf8*)(bx2 + off);
        bf8 A0m = *(const bf8*)(am0 + off);
        bf8 A0w = *(const bf8*)(aw0 + off);
        bf8 A0v = *(const bf8*)(av0 + off);
        bf8 A1m = *(const bf8*)(am1 + off);
        bf8 A1w = *(const bf8*)(aw1 + off);
        bf8 A1v = *(const bf8*)(av1 + off);
        aQ0 = __builtin_amdgcn_mfma_f32_32x32x16_bf16(A0m, vb,  aQ0, 0, 0, 0);
        aV0 = __builtin_amdgcn_mfma_f32_32x32x16_bf16(A0w, vbv, aV0, 0, 0, 0);
        aV0 = __builtin_amdgcn_mfma_f32_32x32x16_bf16(A0v, vb2, aV0, 0, 0, 0);
        aQ1 = __builtin_amdgcn_mfma_f32_32x32x16_bf16(A1m, vb,  aQ1, 0, 0, 0);
        aV1 = __builtin_amdgcn_mfma_f32_32x32x16_bf16(A1w, vbv, aV1, 0, 0, 0);
        aV1 = __builtin_amdgcn_mfma_f32_32x32x16_bf16(A1v, vb2, aV1, 0, 0, 0);
    }

    // write in attn's Q-frag order: [bh][rt][c][l][e]
    const int mrow = mt * 32 + lh;
    const int b = mrow >> 10;
    const int rt = mt & 31;
    const size_t bh_base = ((size_t)(b * NH + head)) * 65536 + (size_t)rt * 2048;
    const float S1 = 0.03125f, S2 = 0.0009765625f;
    #pragma unroll
    for (int i = 0; i < 16; i += 2) {
        const int dh0 = (i & 3) + 8 * (i >> 2) + 4 * h;       // 0..31
        const size_t o = bh_base + (size_t)(dh0 >> 4) * 512
                       + (lh + 32 * ((dh0 >> 3) & 1)) * 8 + (dh0 & 7);
        *(unsigned*)(qmF + o)         = pk(aQ0[i]*S1, aQ0[i+1]*S1);
        *(unsigned*)(qmF + o + 1024)  = pk(aQ1[i]*S1, aQ1[i+1]*S1);   // c += 2
        *(unsigned*)(vqF + o)         = pk(aV0[i]*S2, aV0[i+1]*S2);
        *(unsigned*)(vqF + o + 1024)  = pk(aV1[i]*S2, aV1[i+1]*S2);
    }
}

// Fused causal VDP attention from frag-order planes. All loads coalesced.
__global__ __launch_bounds__(128, 2)
void attn_b(const ushort_t* __restrict__ qmF, const ushort_t* __restrict__ vqF,
            const ushort_t* __restrict__ kmF, const ushort_t* __restrict__ k2F,
            const ushort_t* __restrict__ kvF,
            const ushort_t* __restrict__ vmF, const ushort_t* __restrict__ wF,
            const ushort_t* __restrict__ vvF,
            const float* __restrict__ x,
            float* __restrict__ out0, float* __restrict__ out1)
{
    __shared__ float lds[64][65];

    const int tid  = threadIdx.x;
    const int w    = tid >> 6;
    const int lane = tid & 63;
    const int lh   = lane & 31;
    const int h    = lane >> 5;
    const int lb   = (blockIdx.x & 7) * 128 + (blockIdx.x >> 3);  // XCD-chunked
    const int rb   = 15 - (lb & 15);                              // heavy-first
    const int bh   = lb >> 4;
    const int rt   = rb * 2 + w;                                  // 32-row tile
    const size_t base = (size_t)bh * 65536;

    // persistent Q frags (pre-scaled): qm*2^-5, vq*2^-10, q2 = (qm*2^-5)^2
    bf8 fqm[4], fvq[4], fq2[4];
    {
        const ushort_t* qp = qmF + base + (size_t)rt * 2048 + lane * 8;
        const ushort_t* vp = vqF + base + (size_t)rt * 2048 + lane * 8;
        #pragma unroll
        for (int c = 0; c < 4; ++c) {
            fqm[c] = *(const bf8*)(qp + c * 512);
            fvq[c] = *(const bf8*)(vp + c * 512);
            U8 t; t.v = fqm[c];
            U8 r;
            #pragma unroll
            for (int k = 0; k < 4; ++k) {
                float q0 = b2f(t.s[2*k]), q1 = b2f(t.s[2*k+1]);
                r.u[k] = pk(q0*q0, q1*q1);
            }
            fq2[c] = r.v;
        }
    }

    f16v aN1[2], aN2w[2], aM2[2], aN3[2];
    #pragma unroll
    for (int dt = 0; dt < 2; ++dt) { aN1[dt]=zero16(); aN2w[dt]=zero16(); aM2[dt]=zero16(); aN3[dt]=zero16(); }
    float mrun = -INFINITY, Zrun = 0.f, S2run = 0.f;

    const ushort_t* kb = kmF + base + lane * 8;
    const ushort_t* k2 = k2F + base + lane * 8;
    const ushort_t* kv = kvF + base + lane * 8;
    const ushort_t* vb = vmF + base + lane * 8;
    const ushort_t* wb = wF  + base + lane * 8;
    const ushort_t* xb = vvF + base + lane * 8;

    const int nsub = rt + 1;
    for (int st = 0; st < nsub; ++st) {
        const size_t sb = (size_t)st * 2048;
        // ---- phase 1: scores (coalesced load -> MFMA) ----
        f16v accA = zero16(), accU = zero16();
        #pragma unroll
        for (int c = 0; c < 4; ++c) {
            bf8 A0 = *(const bf8*)(kb + sb + c * 512);
            bf8 A1 = *(const bf8*)(k2 + sb + c * 512);
            bf8 A2 = *(const bf8*)(kv + sb + c * 512);
            accA = __builtin_amdgcn_mfma_f32_32x32x16_bf16(A0, fqm[c], accA, 0, 0, 0);
            accU = __builtin_amdgcn_mfma_f32_32x32x16_bf16(A1, fvq[c], accU, 0, 0, 0);
            accU = __builtin_amdgcn_mfma_f32_32x32x16_bf16(A2, fq2[c], accU, 0, 0, 0);
        }
        if (st == nsub - 1) {                 // diagonal: mask j_loc > lh
            #pragma unroll
            for (int i = 0; i < 16; ++i) {
                const int jl = (i & 3) + 8 * (i >> 2) + 4 * h;
                if (jl > lh) accA[i] = -INFINITY;
            }
        }
        // ---- online softmax with defer-max ----
        float mx = accA[0];
        #pragma unroll
        for (int i = 1; i < 16; ++i) mx = fmaxf(mx, accA[i]);
        mx = fmaxf(mx, __shfl_xor(mx, 32));
        if (!__all(mx <= mrun + 8.f)) {
            const float mnew = fmaxf(mrun, mx);
            const float s1 = __expf(mrun - mnew);
            const float s2 = s1 * s1, s3 = s2 * s1;
            Zrun *= s1; S2run *= s2;
            #pragma unroll
            for (int dt = 0; dt < 2; ++dt) { vscale(aN1[dt],s1); vscale(aN2w[dt],s2); vscale(aM2[dt],s2); vscale(aN3[dt],s3); }
            mrun = mnew;
        }
        float Zt = 0.f, St = 0.f;
        #pragma unroll
        for (int i = 0; i < 16; ++i) {
            const float e = __expf(accA[i] - mrun);
            accA[i] = e;
            Zt += e; St = fmaf(e * e, accU[i], St);
        }
        Zt += __shfl_xor(Zt, 32); St += __shfl_xor(St, 32);
        Zrun += Zt; S2run += St;

        // ---- phase 2: PV ----
        #pragma unroll
        for (int c2 = 0; c2 < 2; ++c2) {
            unsigned pE[4], pE2[4], pEU[4], pE3[4];
            #pragma unroll
            for (int k = 0; k < 4; ++k) {
                const int i0 = 8*c2 + 2*k;
                const float e0 = accA[i0], e1 = accA[i0+1];
                const float q0 = e0*e0, q1 = e1*e1;
                const float t0 = q0*accU[i0], t1 = q1*accU[i0+1];
                pE [k] = pk(e0, e1);
                pE2[k] = pk(q0, q1);
                pEU[k] = pk(t0, t1);
                pE3[k] = pk(t0*e0, t1*e1);
            }
            bf8 BE  = mkB(pE [0], pE [1], pE [2], pE [3], h);
            bf8 BE2 = mkB(pE2[0], pE2[1], pE2[2], pE2[3], h);
            bf8 BEU = mkB(pEU[0], pEU[1], pEU[2], pEU[3], h);
            bf8 BE3 = mkB(pE3[0], pE3[1], pE3[2], pE3[3], h);
            #pragma unroll
            for (int dt = 0; dt < 2; ++dt) {
                const size_t vo = sb + (size_t)(dt * 2 + c2) * 512;
                bf8 Am = *(const bf8*)(vb + vo);
                bf8 Aw = *(const bf8*)(wb + vo);
                bf8 Av = *(const bf8*)(xb + vo);
                aN1[dt]  = __builtin_amdgcn_mfma_f32_32x32x16_bf16(Am, BE,  aN1[dt],  0, 0, 0);
                aN2w[dt] = __builtin_amdgcn_mfma_f32_32x32x16_bf16(Aw, BE2, aN2w[dt], 0, 0, 0);
                aM2[dt]  = __builtin_amdgcn_mfma_f32_32x32x16_bf16(Aw, BEU, aM2[dt],  0, 0, 0);
                aM2[dt]  = __builtin_amdgcn_mfma_f32_32x32x16_bf16(Av, BE2, aM2[dt],  0, 0, 0);
                aN3[dt]  = __builtin_amdgcn_mfma_f32_32x32x16_bf16(Aw, BE3, aN3[dt],  0, 0, 0);
            }
        }
    }

    // ---- epilogue ----
    const float rZ  = 1.f / Zrun;
    const float rZ2 = rZ * rZ;
    const float sS  = S2run * rZ2;
    const int b = bh >> 4, head = bh & 15;

    #pragma unroll
    for (int dt = 0; dt < 2; ++dt)
        #pragma unroll
        for (int i = 0; i < 16; ++i) {
            const int col = 32*dt + (i & 3) + 8*(i >> 2) + 4*h;
            lds[w*32 + lh][col] = aN1[dt][i] * rZ;
        }
    __syncthreads();
    {
        const int row = tid >> 1, half = (tid & 1) * 32;
        const size_t o = ((size_t)b * NS + rb*64 + row) * ND + head * NDH + half;
        #pragma unroll
        for (int q4 = 0; q4 < 32; q4 += 4) {
            float4 t = make_float4(lds[row][half+q4], lds[row][half+q4+1],
                                   lds[row][half+q4+2], lds[row][half+q4+3]);
            float4 xi = *(const float4*)(x + o + q4);
            *(float4*)(out0 + o + q4) = make_float4(t.x+xi.x, t.y+xi.y, t.z+xi.z, t.w+xi.w);
        }
    }
    __syncthreads();
    #pragma unroll
    for (int dt = 0; dt < 2; ++dt)
        #pragma unroll
        for (int i = 0; i < 16; ++i) {
            const int col = 32*dt + (i & 3) + 8*(i >> 2) + 4*h;
            lds[w*32 + lh][col] = rZ2 * fmaf(sS, aN2w[dt][i], aM2[dt][i]) - 2.f*rZ2*rZ*aN3[dt][i];
        }
    __syncthreads();
    {
        const int row = tid >> 1, half = (tid & 1) * 32;
        const size_t o = ((size_t)b * NS + rb*64 + row) * ND + head * NDH + half;
        #pragma unroll
        for (int q4 = 0; q4 < 32; q4 += 4) {
            float4 t = make_float4(lds[row][half+q4], lds[row][half+q4+1],
                                   lds[row][half+q4+2], lds[row][half+q4+3]);
            *(float4*)(out1 + o + q4) = t;
        }
    }
}

// ===========================================================================
// FALLBACK PATH (round-4 kernels, ~16 MB ws) — used if ws_size is too small.
// ===========================================================================
__global__ __launch_bounds__(256, 3)
void qproj_fb(const float* __restrict__ x, const float* __restrict__ vx,
              const float* __restrict__ Wm, const float* __restrict__ Wv,
              ushort_t* __restrict__ qm_ws, ushort_t* __restrict__ vq_ws)
{
    const int tid  = threadIdx.x;
    const int w    = tid >> 6;
    const int lane = tid & 63;
    const int lh   = lane & 31;
    const int h    = lane >> 5;
    const int head = blockIdx.x;
    const int mb   = blockIdx.y;
    const int mrow = mb * 128 + w * 32 + lh;

    f16v aQ0 = zero16(), aQ1 = zero16(), aV0 = zero16(), aV1 = zero16();

    const float* xr = x  + (size_t)mrow * ND;
    const float* vr = vx + (size_t)mrow * ND;
    const float* w0 = Wm + (size_t)(head*64 +      lh) * ND;
    const float* w1 = Wm + (size_t)(head*64 + 32 + lh) * ND;
    const float* v0 = Wv + (size_t)(head*64 +      lh) * ND;
    const float* v1 = Wv + (size_t)(head*64 + 32 + lh) * ND;

    for (int kc = 0; kc < 64; ++kc) {
        const int ko = kc * 16 + 8 * h;
        float4 xa = *(const float4*)(xr + ko); float4 xb = *(const float4*)(xr + ko + 4);
        float4 va = *(const float4*)(vr + ko); float4 vb = *(const float4*)(vr + ko + 4);
        U8 fx_, fvx_, fx2_;
        fx_.u[0]  = pk(xa.x, xa.y); fx_.u[1]  = pk(xa.z, xa.w);
        fx_.u[2]  = pk(xb.x, xb.y); fx_.u[3]  = pk(xb.z, xb.w);
        fvx_.u[0] = pk(va.x, va.y); fvx_.u[1] = pk(va.z, va.w);
        fvx_.u[2] = pk(vb.x, vb.y); fvx_.u[3] = pk(vb.z, vb.w);
        fx2_.u[0] = pk(xa.x*xa.x, xa.y*xa.y); fx2_.u[1] = pk(xa.z*xa.z, xa.w*xa.w);
        fx2_.u[2] = pk(xb.x*xb.x, xb.y*xb.y); fx2_.u[3] = pk(xb.z*xb.z, xb.w*xb.w);
        {
            float4 ma = *(const float4*)(w0 + ko); float4 mb4 = *(const float4*)(w0 + ko + 4);
            float4 wa = *(const float4*)(v0 + ko); float4 wb  = *(const float4*)(v0 + ko + 4);
            U8 fm_, fw2_, fv_;
            fm_.u[0]  = pk(ma.x, ma.y);   fm_.u[1] = pk(ma.z, ma.w);
            fm_.u[2]  = pk(mb4.x, mb4.y); fm_.u[3] = pk(mb4.z, mb4.w);
            fv_.u[0]  = pk(wa.x, wa.y);   fv_.u[1] = pk(wa.z, wa.w);
            fv_.u[2]  = pk(wb.x, wb.y);   fv_.u[3] = pk(wb.z, wb.w);
            fw2_.u[0] = pk(fmaf(ma.x,ma.x,wa.x),  fmaf(ma.y,ma.y,wa.y));
            fw2_.u[1] = pk(fmaf(ma.z,ma.z,wa.z),  fmaf(ma.w,ma.w,wa.w));
            fw2_.u[2] = pk(fmaf(mb4.x,mb4.x,wb.x), fmaf(mb4.y,mb4.y,wb.y));
            fw2_.u[3] = pk(fmaf(mb4.z,mb4.z,wb.z), fmaf(mb4.w,mb4.w,wb.w));
            aQ0 = __builtin_amdgcn_mfma_f32_32x32x16_bf16(fm_.v,  fx_.v,  aQ0, 0, 0, 0);
            aV0 = __builtin_amdgcn_mfma_f32_32x32x16_bf16(fw2_.v, fvx_.v, aV0, 0, 0, 0);
            aV0 = __builtin_amdgcn_mfma_f32_32x32x16_bf16(fv_.v,  fx2_.v, aV0, 0, 0, 0);
        }
        {
            float4 ma = *(const float4*)(w1 + ko); float4 mb4 = *(const float4*)(w1 + ko + 4);
            float4 wa = *(const float4*)(v1 + ko); float4 wb  = *(const float4*)(v1 + ko + 4);
            U8 fm_, fw2_, fv_;
            fm_.u[0]  = pk(ma.x, ma.y);   fm_.u[1] = pk(ma.z, ma.w);
            fm_.u[2]  = pk(mb4.x, mb4.y); fm_.u[3] = pk(mb4.z, mb4.w);
            fv_.u[0]  = pk(wa.x, wa.y);   fv_.u[1] = pk(wa.z, wa.w);
            fv_.u[2]  = pk(wb.x, wb.y);   fv_.u[3] = pk(wb.z, wb.w);
            fw2_.u[0] = pk(fmaf(ma.x,ma.x,wa.x),  fmaf(ma.y,ma.y,wa.y));
            fw2_.u[1] = pk(fmaf(ma.z,ma.z,wa.z),  fmaf(ma.w,ma.w,wa.w));
            fw2_.u[2] = pk(fmaf(mb4.x,mb4.x,wb.x), fmaf(mb4.y,mb4.y,wb.y));
            fw2_.u[3] = pk(fmaf(mb4.z,mb4.z,wb.z), fmaf(mb4.w,mb4.w,wb.w));
            aQ1 = __builtin_amdgcn_mfma_f32_32x32x16_bf16(fm_.v,  fx_.v,  aQ1, 0, 0, 0);
            aV1 = __builtin_amdgcn_mfma_f32_32x32x16_bf16(fw2_.v, fvx_.v, aV1, 0, 0, 0);
            aV1 = __builtin_amdgcn_mfma_f32_32x32x16_bf16(fv_.v,  fx2_.v, aV1, 0, 0, 0);
        }
    }
    const int b = mrow >> 10, srow = mrow & 1023;
    ushort_t* qp = qm_ws + (((size_t)(b * NH + head)) * NS + srow) * NDH;
    ushort_t* vp = vq_ws + (((size_t)(b * NH + head)) * NS + srow) * NDH;
    #pragma unroll
    for (int i = 0; i < 16; i += 2) {
        const int dh0 = (i & 3) + 8 * (i >> 2) + 4 * h;
        *(unsigned*)(qp + dh0)      = pk(aQ0[i], aQ0[i+1]);
        *(unsigned*)(qp + 32 + dh0) = pk(aQ1[i], aQ1[i+1]);
        *(unsigned*)(vp + dh0)      = pk(aV0[i], aV0[i+1]);
        *(unsigned*)(vp + 32 + dh0) = pk(aV1[i], aV1[i+1]);
    }
}

__global__ __launch_bounds__(256, 2)
void attn_fb(const ushort_t* __restrict__ qm_ws, const ushort_t* __restrict__ vq_ws,
             const float* __restrict__ K,  const float* __restrict__ VK,
             const float* __restrict__ Vv, const float* __restrict__ VV,
             const float* __restrict__ x,
             float* __restrict__ out0, float* __restrict__ out1)
{
    __shared__ float lds[128][65];
    const int tid  = threadIdx.x;
    const int w    = tid >> 6;
    const int lane = tid & 63;
    const int lh   = lane & 31;
    const int h    = lane >> 5;
    const int blk  = blockIdx.x;
    const int rb   = 7 - (blk & 7);
    const int bh   = blk >> 3;
    const int row0 = rb * 128 + w * 32;
    const int rg   = row0 + lh;
    const size_t base = (size_t)bh * NS * NDH;

    bf8 fqm[4], fvq[4], fq2[4];
    {
        const ushort_t* qp = qm_ws + base + (size_t)rg * NDH;
        const ushort_t* vp = vq_ws + base + (size_t)rg * NDH;
        #pragma unroll
        for (int c = 0; c < 4; ++c) {
            fqm[c] = *(const bf8*)(qp + 16*c + 8*h);
            fvq[c] = *(const bf8*)(vp + 16*c + 8*h);
            U8 t; t.v = fqm[c];
            U8 r;
            #pragma unroll
            for (int k = 0; k < 4; ++k) {
                float q0 = b2f(t.s[2*k]), q1 = b2f(t.s[2*k+1]);
                r.u[k] = pk(q0*q0, q1*q1);
            }
            fq2[c] = r.v;
        }
    }
    f16v aN1[2], aN2w[2], aM2[2], aN3[2];
    #pragma unroll
    for (int dt = 0; dt < 2; ++dt) { aN1[dt]=zero16(); aN2w[dt]=zero16(); aM2[dt]=zero16(); aN3[dt]=zero16(); }
    float mrun = -INFINITY, Zrun = 0.f, S2run = 0.f;

    const int nsub = 4 * rb + w + 1;
    for (int st = 0; st < nsub; ++st) {
        const int j0 = st * 32;
        f16v accA = zero16(), accU = zero16();
        #pragma unroll
        for (int c = 0; c < 4; ++c) {
            const float* kp = K  + base + (size_t)(j0 + lh) * NDH + 16*c + 8*h;
            const float* up = VK + base + (size_t)(j0 + lh) * NDH + 16*c + 8*h;
            float4 k0 = *(const float4*)kp, k1 = *(const float4*)(kp + 4);
            float4 u0 = *(const float4*)up, u1 = *(const float4*)(up + 4);
            U8 fkm, fk2, fkv;
            fkm.u[0] = pk(k0.x, k0.y); fkm.u[1] = pk(k0.z, k0.w);
            fkm.u[2] = pk(k1.x, k1.y); fkm.u[3] = pk(k1.z, k1.w);
            fkv.u[0] = pk(u0.x, u0.y); fkv.u[1] = pk(u0.z, u0.w);
            fkv.u[2] = pk(u1.x, u1.y); fkv.u[3] = pk(u1.z, u1.w);
            fk2.u[0] = pk(fmaf(k0.x,k0.x,u0.x), fmaf(k0.y,k0.y,u0.y));
            fk2.u[1] = pk(fmaf(k0.z,k0.z,u0.z), fmaf(k0.w,k0.w,u0.w));
            fk2.u[2] = pk(fmaf(k1.x,k1.x,u1.x), fmaf(k1.y,k1.y,u1.y));
            fk2.u[3] = pk(fmaf(k1.z,k1.z,u1.z), fmaf(k1.w,k1.w,u1.w));
            accA = __builtin_amdgcn_mfma_f32_32x32x16_bf16(fkm.v, fqm[c], accA, 0, 0, 0);
            accU = __builtin_amdgcn_mfma_f32_32x32x16_bf16(fk2.v, fvq[c], accU, 0, 0, 0);
            accU = __builtin_amdgcn_mfma_f32_32x32x16_bf16(fkv.v, fq2[c], accU, 0, 0, 0);
        }
        float a[16], u[16];
        #pragma unroll
        for (int i = 0; i < 16; ++i) { a[i] = accA[i] * 0.03125f; u[i] = accU[i] * 0.0009765625f; }
        if (st == nsub - 1) {
            #pragma unroll
            for (int i = 0; i < 16; ++i) {
                const int jl = (i & 3) + 8 * (i >> 2) + 4 * h;
                if (jl > lh) a[i] = -INFINITY;
            }
        }
        float mx = a[0];
        #pragma unroll
        for (int i = 1; i < 16; ++i) mx = fmaxf(mx, a[i]);
        mx = fmaxf(mx, __shfl_xor(mx, 32));
        const float mnew = fmaxf(mrun, mx);
        const float s1 = __expf(mrun - mnew);
        float ex[16];
        float Zt = 0.f, St = 0.f;
        #pragma unroll
        for (int i = 0; i < 16; ++i) {
            float ee = __expf(a[i] - mnew);
            ex[i] = ee; Zt += ee; St = fmaf(ee*ee, u[i], St);
        }
        Zt += __shfl_xor(Zt, 32); St += __shfl_xor(St, 32);
        const float s2 = s1*s1, s3 = s2*s1;
        Zrun = fmaf(Zrun, s1, Zt); S2run = fmaf(S2run, s2, St); mrun = mnew;
        #pragma unroll
        for (int dt = 0; dt < 2; ++dt) { vscale(aN1[dt],s1); vscale(aN2w[dt],s2); vscale(aM2[dt],s2); vscale(aN3[dt],s3); }
        unsigned PE[8], PE2[8], PEU[8], PE3[8];
        #pragma unroll
        for (int k = 0; k < 8; ++k) {
            float e0 = ex[2*k], e1 = ex[2*k+1];
            float q0 = e0*e0, q1 = e1*e1;
            float t0 = q0*u[2*k], t1 = q1*u[2*k+1];
            PE[k] = pk(e0, e1); PE2[k] = pk(q0, q1); PEU[k] = pk(t0, t1); PE3[k] = pk(t0*e0, t1*e1);
        }
        #pragma unroll
        for (int c2 = 0; c2 < 2; ++c2) {
            bf8 BE  = mkB(PE [4*c2], PE [4*c2+1], PE [4*c2+2], PE [4*c2+3], h);
            bf8 BE2 = mkB(PE2[4*c2], PE2[4*c2+1], PE2[4*c2+2], PE2[4*c2+3], h);
            bf8 BEU = mkB(PEU[4*c2], PEU[4*c2+1], PEU[4*c2+2], PEU[4*c2+3], h);
            bf8 BE3 = mkB(PE3[4*c2], PE3[4*c2+1], PE3[4*c2+2], PE3[4*c2+3], h);
            #pragma unroll
            for (int dt = 0; dt < 2; ++dt) {
                const float* vmb = Vv + base + (size_t)(j0 + 16*c2 + 8*h) * NDH + 32*dt + lh;
                const float* vvb = VV + base + (size_t)(j0 + 16*c2 + 8*h) * NDH + 32*dt + lh;
                float vm[8], vv[8];
                #pragma unroll
                for (int e = 0; e < 8; ++e) { vm[e] = vmb[e * NDH]; vv[e] = vvb[e * NDH]; }
                U8 fvm, fw, fvv;
                #pragma unroll
                for (int k = 0; k < 4; ++k) {
                    float w0f = fmaf(vm[2*k],   vm[2*k],   vv[2*k]);
                    float w1f = fmaf(vm[2*k+1], vm[2*k+1], vv[2*k+1]);
                    fvm.u[k] = pk(vm[2*k], vm[2*k+1]);
                    fw.u[k]  = pk(w0f, w1f);
                    fvv.u[k] = pk(vv[2*k], vv[2*k+1]);
                }
                aN1[dt]  = __builtin_amdgcn_mfma_f32_32x32x16_bf16(fvm.v, BE,  aN1[dt],  0, 0, 0);
                aN2w[dt] = __builtin_amdgcn_mfma_f32_32x32x16_bf16(fw.v,  BE2, aN2w[dt], 0, 0, 0);
                aM2[dt]  = __builtin_amdgcn_mfma_f32_32x32x16_bf16(fw.v,  BEU, aM2[dt],  0, 0, 0);
                aM2[dt]  = __builtin_amdgcn_mfma_f32_32x32x16_bf16(fvv.v, BE2, aM2[dt],  0, 0, 0);
                aN3[dt]  = __builtin_amdgcn_mfma_f32_32x32x16_bf16(fw.v,  BE3, aN3[dt],  0, 0, 0);
            }
        }
    }
    const float rZ  = 1.f / Zrun;
    const float rZ2 = rZ * rZ;
    const float sS  = S2run * rZ2;
    const int b = bh >> 4, head = bh & 15;
    #pragma unroll
    for (int dt = 0; dt < 2; ++dt)
        #pragma unroll
        for (int i = 0; i < 16; ++i) {
            const int col = 32*dt + (i & 3) + 8*(i >> 2) + 4*h;
            lds[w*32 + lh][col] = aN1[dt][i] * rZ;
        }
    __syncthreads();
    {
        const int row = tid >> 1, half = (tid & 1) * 32;
        const size_t o = ((size_t)b * NS + rb*128 + row) * ND + head * NDH + half;
        #pragma unroll
        for (int q4 = 0; q4 < 32; q4 += 4) {
            float4 t = make_float4(lds[row][half+q4], lds[row][half+q4+1],
                                   lds[row][half+q4+2], lds[row][half+q4+3]);
            float4 xi = *(const float4*)(x + o + q4);
            *(float4*)(out0 + o + q4) = make_float4(t.x+xi.x, t.y+xi.y, t.z+xi.z, t.w+xi.w);
        }
    }
    __syncthreads();
    #pragma unroll
    for (int dt = 0; dt < 2; ++dt)
        #pragma unroll
        for (int i = 0; i < 16; ++i) {
            const int col = 32*dt + (i & 3) + 8*(i >> 2) + 4*h;
            lds[w*32 + lh][col] = rZ2 * fmaf(sS, aN2w[dt][i], aM2[dt][i]) - 2.f*rZ2*rZ*aN3[dt][i];
        }
    __syncthreads();
    {
        const int row = tid >> 1, half = (tid & 1) * 32;
        const size_t o = ((size_t)b * NS + rb*128 + row) * ND + head * NDH + half;
        #pragma unroll
        for (int q4 = 0; q4 < 32; q4 += 4) {
            float4 t = make_float4(lds[row][half+q4], lds[row][half+q4+1],
                                   lds[row][half+q4+2], lds[row][half+q4+3]);
            *(float4*)(out1 + o + q4) = t;
        }
    }
}

extern "C" void kernel_launch(void* const* d_in, const int* in_sizes, int n_in,
                              void* d_out, int out_size, void* d_ws, size_t ws_size,
                              hipStream_t stream)
{
    (void)in_sizes; (void)n_in; (void)out_size;
    const float* x  = (const float*)d_in[0];
    const float* vx = (const float*)d_in[1];
    const float* K  = (const float*)d_in[2];
    const float* VK = (const float*)d_in[3];
    const float* Vv = (const float*)d_in[4];
    const float* VV = (const float*)d_in[5];
    const float* Wm = (const float*)d_in[6];
    const float* Wv = (const float*)d_in[7];

    float* out0 = (float*)d_out;
    float* out1 = out0 + (size_t)NB * NS * ND;

    const size_t M4 = 4194304, M1 = 1048576;
    const size_t need = (11 * M4 + 3 * M1) * 2;   // ~94.4 MB

    ushort_t* qm = (ushort_t*)d_ws;
    ushort_t* vq = qm + M4;

    if (ws_size >= need) {
        ushort_t* kmF = vq  + M4;
        ushort_t* k2F = kmF + M4;
        ushort_t* kvF = k2F + M4;
        ushort_t* vmF = kvF + M4;
        ushort_t* wF  = vmF + M4;
        ushort_t* vvF = wF  + M4;
        ushort_t* fxF = vvF + M4;
        ushort_t* fvxF= fxF + M4;
        ushort_t* fx2F= fvxF+ M4;
        ushort_t* fmF = fx2F+ M4;
        ushort_t* fw2F= fmF + M1;
        ushort_t* fvF = fw2F+ M1;

        prep_xw<<<2560, 256, 0, stream>>>(x, vx, Wm, Wv, fxF, fvxF, fx2F, fmF, fw2F, fvF);
        prep_kv<<<dim3(64, 32), 256, 0, stream>>>(K, VK, Vv, VV, kmF, k2F, kvF, vmF, wF, vvF);
        qproj_b<<<dim3(NH, 32), 256, 0, stream>>>(fxF, fvxF, fx2F, fmF, fw2F, fvF, qm, vq);
        attn_b<<<1024, 128, 0, stream>>>(qm, vq, kmF, k2F, kvF, vmF, wF, vvF, x, out0, out1);
    } else {
        qproj_fb<<<dim3(NH, 32), 256, 0, stream>>>(x, vx, Wm, Wv, qm, vq);
        attn_fb<<<64 * 8, 256, 0, stream>>>(qm, vq, K, VK, Vv, VV, x, out0, out1);
    }
}

// Round 7
// 177.763 us; speedup vs baseline: 13.5498x; 1.3535x over previous
//
#include <hip/hip_runtime.h>
#include <hip/hip_bf16.h>
#include <math.h>

#define NB 4
#define NS 1024
#define ND 1024
#define NH 16
#define NDH 64
#define M4 4194304
#define M1 1048576

typedef float f16v __attribute__((ext_vector_type(16)));
typedef short bf8 __attribute__((ext_vector_type(8)));
typedef unsigned short ushort_t;

union U8 { bf8 v; unsigned u[4]; unsigned short s[8]; };

__device__ __forceinline__ unsigned pk(float lo, float hi) {
    __hip_bfloat162 h2 = __float22bfloat162_rn(make_float2(lo, hi));
    return *reinterpret_cast<unsigned*>(&h2);
}
__device__ __forceinline__ unsigned short f2b(float f) {
    unsigned u = __float_as_uint(f);
    unsigned r = (u + 0x7fffu + ((u >> 16) & 1u)) >> 16;   // RNE
    return (unsigned short)r;
}
__device__ __forceinline__ float b2f(unsigned short h) {
    return __uint_as_float(((unsigned)h) << 16);
}
__device__ __forceinline__ f16v zero16() {
    f16v z;
    #pragma unroll
    for (int i = 0; i < 16; ++i) z[i] = 0.f;
    return z;
}
__device__ __forceinline__ void vscale(f16v& v, float s) {
    #pragma unroll
    for (int i = 0; i < 16; ++i) v[i] *= s;
}

// async global->LDS, 16B per lane (wave-uniform base + lane*16 layout)
__device__ __forceinline__ void gl_lds16(const ushort_t* g, ushort_t* l) {
    __builtin_amdgcn_global_load_lds(
        (const __attribute__((address_space(1))) unsigned int*)g,
        (__attribute__((address_space(3))) unsigned int*)l,
        16, 0, 0);
}

// Build PV B-frag (coef[j, r], K=16 chunk) from packed pairs p0..p3.
__device__ __forceinline__ bf8 mkB(unsigned p0, unsigned p1, unsigned p2, unsigned p3, int h) {
    unsigned own0 = h ? p2 : p0;
    unsigned own1 = h ? p3 : p1;
    unsigned ct0  = h ? p0 : p2;
    unsigned ct1  = h ? p1 : p3;
    unsigned x0 = (unsigned)__shfl_xor((int)ct0, 32);
    unsigned x1 = (unsigned)__shfl_xor((int)ct1, 32);
    U8 B;
    B.u[0] = h ? x0 : own0;
    B.u[1] = h ? x1 : own1;
    B.u[2] = h ? own0 : x0;
    B.u[3] = h ? own1 : x1;
    return B.v;
}

// ===========================================================================
// Frag-order layouts (unchanged from round 6):
// K planes  [bh][s][c][lane][8]   (planes kmF,k2F,kvF consecutive, stride M4)
// V planes  [bh][s][dt*2+c2][lane][8] (vmF,wF,vvF consecutive, stride M4)
// x planes  [mt][kc][lane][8]     (fxF,fvxF,fx2F consecutive, stride M4)
// W planes  [nt][kc][lane][8]     (fmF,fw2F,fvF consecutive, stride M1)
// qm/vq     [bh][rt][c][lane][8]
// ===========================================================================

__global__ __launch_bounds__(256)
void prep_xw(const float* __restrict__ x, const float* __restrict__ vx,
             const float* __restrict__ Wm, const float* __restrict__ Wv,
             ushort_t* __restrict__ fx, ushort_t* __restrict__ fvx, ushort_t* __restrict__ fx2,
             ushort_t* __restrict__ fm, ushort_t* __restrict__ fw2, ushort_t* __restrict__ fv)
{
    const size_t g = (size_t)blockIdx.x * 256 + threadIdx.x;
    if (g < 524288) {
        const size_t g0 = g * 8;
        const int row = (int)(g0 >> 10), k0 = (int)(g0 & 1023);
        const size_t fo = ((size_t)(row >> 5) * 64 + (k0 >> 4)) * 512
                        + ((row & 31) + 32 * ((k0 >> 3) & 1)) * 8;
        float a[8], c[8];
        *(float4*)(a)   = *(const float4*)(x + g0);  *(float4*)(a+4) = *(const float4*)(x + g0 + 4);
        *(float4*)(c)   = *(const float4*)(vx + g0); *(float4*)(c+4) = *(const float4*)(vx + g0 + 4);
        *(uint4*)(fx  + fo) = make_uint4(pk(a[0],a[1]), pk(a[2],a[3]), pk(a[4],a[5]), pk(a[6],a[7]));
        *(uint4*)(fvx + fo) = make_uint4(pk(c[0],c[1]), pk(c[2],c[3]), pk(c[4],c[5]), pk(c[6],c[7]));
        *(uint4*)(fx2 + fo) = make_uint4(pk(a[0]*a[0],a[1]*a[1]), pk(a[2]*a[2],a[3]*a[3]),
                                         pk(a[4]*a[4],a[5]*a[5]), pk(a[6]*a[6],a[7]*a[7]));
    } else {
        const size_t g0 = (g - 524288) * 8;
        const int row = (int)(g0 >> 10), k0 = (int)(g0 & 1023);
        const size_t fo = ((size_t)(row >> 5) * 64 + (k0 >> 4)) * 512
                        + ((row & 31) + 32 * ((k0 >> 3) & 1)) * 8;
        float a[8], c[8];
        *(float4*)(a)   = *(const float4*)(Wm + g0); *(float4*)(a+4) = *(const float4*)(Wm + g0 + 4);
        *(float4*)(c)   = *(const float4*)(Wv + g0); *(float4*)(c+4) = *(const float4*)(Wv + g0 + 4);
        *(uint4*)(fm  + fo) = make_uint4(pk(a[0],a[1]), pk(a[2],a[3]), pk(a[4],a[5]), pk(a[6],a[7]));
        *(uint4*)(fv  + fo) = make_uint4(pk(c[0],c[1]), pk(c[2],c[3]), pk(c[4],c[5]), pk(c[6],c[7]));
        *(uint4*)(fw2 + fo) = make_uint4(pk(fmaf(a[0],a[0],c[0]), fmaf(a[1],a[1],c[1])),
                                         pk(fmaf(a[2],a[2],c[2]), fmaf(a[3],a[3],c[3])),
                                         pk(fmaf(a[4],a[4],c[4]), fmaf(a[5],a[5],c[5])),
                                         pk(fmaf(a[6],a[6],c[6]), fmaf(a[7],a[7],c[7])));
    }
}

__global__ __launch_bounds__(256)
void prep_kv(const float* __restrict__ K,  const float* __restrict__ VK,
             const float* __restrict__ Vv, const float* __restrict__ VV,
             ushort_t* __restrict__ kmF, ushort_t* __restrict__ k2F, ushort_t* __restrict__ kvF,
             ushort_t* __restrict__ vmF, ushort_t* __restrict__ wF,  ushort_t* __restrict__ vvF)
{
    __shared__ ushort_t Lm[2048], Lw[2048], Lv[2048];
    const int tid = threadIdx.x;
    const int bh = blockIdx.x, s = blockIdx.y;
    const int jp  = tid >> 3;
    const int dh0 = (tid & 7) * 8;
    const size_t gin = ((size_t)bh * NS + s * 32 + jp) * NDH + dh0;
    const size_t sbase = ((size_t)bh * 32 + s) * 2048;

    float kk[8], uu[8], vm[8], vv[8];
    *(float4*)(kk)   = *(const float4*)(K  + gin); *(float4*)(kk+4) = *(const float4*)(K  + gin + 4);
    *(float4*)(uu)   = *(const float4*)(VK + gin); *(float4*)(uu+4) = *(const float4*)(VK + gin + 4);
    *(float4*)(vm)   = *(const float4*)(Vv + gin); *(float4*)(vm+4) = *(const float4*)(Vv + gin + 4);
    *(float4*)(vv)   = *(const float4*)(VV + gin); *(float4*)(vv+4) = *(const float4*)(VV + gin + 4);

    const size_t kout = sbase + (size_t)((tid & 7) >> 1) * 512
                      + (jp + 32 * ((tid & 7) & 1)) * 8;
    unsigned o0[4], o1[4], o2[4];
    #pragma unroll
    for (int t = 0; t < 4; ++t) {
        o0[t] = pk(kk[2*t], kk[2*t+1]);
        o1[t] = pk(fmaf(kk[2*t],kk[2*t],uu[2*t]), fmaf(kk[2*t+1],kk[2*t+1],uu[2*t+1]));
        o2[t] = pk(uu[2*t], uu[2*t+1]);
    }
    *(uint4*)(kmF + kout) = make_uint4(o0[0],o0[1],o0[2],o0[3]);
    *(uint4*)(k2F + kout) = make_uint4(o1[0],o1[1],o1[2],o1[3]);
    *(uint4*)(kvF + kout) = make_uint4(o2[0],o2[1],o2[2],o2[3]);

    #pragma unroll
    for (int e = 0; e < 8; ++e) {
        const int dh = dh0 + e;
        const int idx = ((dh >> 5) * 2 + (jp >> 4)) * 512
                      + ((dh & 31) + 32 * ((jp >> 3) & 1)) * 8 + (jp & 7);
        Lm[idx] = f2b(vm[e]);
        Lw[idx] = f2b(fmaf(vm[e], vm[e], vv[e]));
        Lv[idx] = f2b(vv[e]);
    }
    __syncthreads();
    const size_t vout = sbase + (size_t)tid * 8;
    *(uint4*)(vmF + vout) = *(const uint4*)(Lm + tid * 8);
    *(uint4*)(wF  + vout) = *(const uint4*)(Lw + tid * 8);
    *(uint4*)(vvF + vout) = *(const uint4*)(Lv + tid * 8);
}

// ---------------------------------------------------------------------------
// qproj: 4 waves (4 mt tiles) share one head's W frags via 2-phase LDS staging.
// ---------------------------------------------------------------------------
__global__ __launch_bounds__(256, 2)
void qproj_b(const ushort_t* __restrict__ xplanes,   // fxF (3 planes, stride M4)
             const ushort_t* __restrict__ wplanes,   // fmF (3 planes, stride M1)
             ushort_t* __restrict__ qmF, ushort_t* __restrict__ vqF)
{
    __shared__ ushort_t wstg[2][12 * 512];           // 24 KiB, dbuf of kc-pairs

    const int tid  = threadIdx.x;
    const int w    = tid >> 6;
    const int lane = tid & 63;
    const int lh   = lane & 31;
    const int h    = lane >> 5;
    const int head = blockIdx.x;
    const int mb   = blockIdx.y;
    const int mt   = mb * 4 + w;
    const int nt   = head * 2 + (w & 1);             // this wave stages (nt, kcL=w>>1)

    f16v aQ0 = zero16(), aQ1 = zero16(), aV0 = zero16(), aV1 = zero16();

    const ushort_t* xb = xplanes + (size_t)mt * 64 * 512 + lane * 8;
    const ushort_t* wsrc = wplanes + ((size_t)nt * 64 + (w >> 1)) * 512 + lane * 8;

    // prologue: stage pair 0
    #pragma unroll
    for (int q = 0; q < 3; ++q)
        gl_lds16(wsrc + (size_t)q * M1, &wstg[0][(3 * w + q) * 512 + lane * 8]);
    __syncthreads();

    for (int t = 0; t < 32; ++t) {
        const int cur = t & 1;
        if (t + 1 < 32) {
            #pragma unroll
            for (int q = 0; q < 3; ++q)
                gl_lds16(wsrc + (size_t)q * M1 + (size_t)(2 * (t + 1)) * 512,
                         &wstg[cur ^ 1][(3 * w + q) * 512 + lane * 8]);
        }
        const ushort_t* sc = wstg[cur];
        #pragma unroll
        for (int kcL = 0; kcL < 2; ++kcL) {
            const int off = (2 * t + kcL) * 512;
            bf8 bx  = *(const bf8*)(xb + 0 * (size_t)M4 + off);
            bf8 bvx = *(const bf8*)(xb + 1 * (size_t)M4 + off);
            bf8 bx2 = *(const bf8*)(xb + 2 * (size_t)M4 + off);
            bf8 A0m = *(const bf8*)(sc + (3 * (2 * kcL + 0) + 0) * 512 + lane * 8);
            bf8 A0w = *(const bf8*)(sc + (3 * (2 * kcL + 0) + 1) * 512 + lane * 8);
            bf8 A0v = *(const bf8*)(sc + (3 * (2 * kcL + 0) + 2) * 512 + lane * 8);
            bf8 A1m = *(const bf8*)(sc + (3 * (2 * kcL + 1) + 0) * 512 + lane * 8);
            bf8 A1w = *(const bf8*)(sc + (3 * (2 * kcL + 1) + 1) * 512 + lane * 8);
            bf8 A1v = *(const bf8*)(sc + (3 * (2 * kcL + 1) + 2) * 512 + lane * 8);
            aQ0 = __builtin_amdgcn_mfma_f32_32x32x16_bf16(A0m, bx,  aQ0, 0, 0, 0);
            aV0 = __builtin_amdgcn_mfma_f32_32x32x16_bf16(A0w, bvx, aV0, 0, 0, 0);
            aV0 = __builtin_amdgcn_mfma_f32_32x32x16_bf16(A0v, bx2, aV0, 0, 0, 0);
            aQ1 = __builtin_amdgcn_mfma_f32_32x32x16_bf16(A1m, bx,  aQ1, 0, 0, 0);
            aV1 = __builtin_amdgcn_mfma_f32_32x32x16_bf16(A1w, bvx, aV1, 0, 0, 0);
            aV1 = __builtin_amdgcn_mfma_f32_32x32x16_bf16(A1v, bx2, aV1, 0, 0, 0);
        }
        __syncthreads();
    }

    const int mrow = mt * 32 + lh;
    const int b = mrow >> 10;
    const int rt = mt & 31;
    const size_t bh_base = ((size_t)(b * NH + head)) * 65536 + (size_t)rt * 2048;
    const float S1 = 0.03125f, S2 = 0.0009765625f;
    #pragma unroll
    for (int i = 0; i < 16; i += 2) {
        const int dh0 = (i & 3) + 8 * (i >> 2) + 4 * h;
        const size_t o = bh_base + (size_t)(dh0 >> 4) * 512
                       + (lh + 32 * ((dh0 >> 3) & 1)) * 8 + (dh0 & 7);
        *(unsigned*)(qmF + o)         = pk(aQ0[i]*S1, aQ0[i+1]*S1);
        *(unsigned*)(qmF + o + 1024)  = pk(aQ1[i]*S1, aQ1[i+1]*S1);
        *(unsigned*)(vqF + o)         = pk(aV0[i]*S2, aV0[i+1]*S2);
        *(unsigned*)(vqF + o + 1024)  = pk(aV1[i]*S2, aV1[i+1]*S2);
    }
}

// ---------------------------------------------------------------------------
// attn: 4 waves (rt = 4rb..4rb+3, same bh) share K/V subtile planes via
// 2-phase double-buffered LDS staging (global_load_lds, 24KB/subtile).
// ---------------------------------------------------------------------------
__global__ __launch_bounds__(256, 2)
void attn_b(const ushort_t* __restrict__ qmF, const ushort_t* __restrict__ vqF,
            const ushort_t* __restrict__ planes,     // kmF (6 planes, stride M4)
            const float* __restrict__ x,
            float* __restrict__ out0, float* __restrict__ out1)
{
    __shared__ union {
        ushort_t stg[2][6 * 2048];   // 48 KiB staging
        float ep[128][66];           // 33.8 KiB epilogue (reused after loop)
    } sm;

    const int tid  = threadIdx.x;
    const int w    = tid >> 6;
    const int lane = tid & 63;
    const int lh   = lane & 31;
    const int h    = lane >> 5;
    const int blk  = blockIdx.x;
    const int lb   = (blk & 7) * 64 + (blk >> 3);    // XCD-chunked
    const int rb   = 7 - (lb & 7);                   // heavy-first
    const int bh   = lb >> 3;
    const int rt   = rb * 4 + w;                     // this wave's 32-row tile
    const size_t base = (size_t)bh * 65536;

    // persistent Q frags (pre-scaled)
    bf8 fqm[4], fvq[4], fq2[4];
    {
        const ushort_t* qp = qmF + base + (size_t)rt * 2048 + lane * 8;
        const ushort_t* vp = vqF + base + (size_t)rt * 2048 + lane * 8;
        #pragma unroll
        for (int c = 0; c < 4; ++c) {
            fqm[c] = *(const bf8*)(qp + c * 512);
            fvq[c] = *(const bf8*)(vp + c * 512);
            U8 t; t.v = fqm[c];
            U8 r;
            #pragma unroll
            for (int k = 0; k < 4; ++k) {
                float q0 = b2f(t.s[2*k]), q1 = b2f(t.s[2*k+1]);
                r.u[k] = pk(q0*q0, q1*q1);
            }
            fq2[c] = r.v;
        }
    }

    f16v aN1[2], aN2w[2], aM2[2], aN3[2];
    #pragma unroll
    for (int dt = 0; dt < 2; ++dt) { aN1[dt]=zero16(); aN2w[dt]=zero16(); aM2[dt]=zero16(); aN3[dt]=zero16(); }
    float mrun = -INFINITY, Zrun = 0.f, S2run = 0.f;

    const int nstage = 4 * rb + 4;
    // prologue: stage subtile 0 -> buf 0 (wave w stages quarter w of each plane)
    #pragma unroll
    for (int p = 0; p < 6; ++p)
        gl_lds16(planes + (size_t)p * M4 + base + w * 512 + lane * 8,
                 &sm.stg[0][p * 2048 + w * 512 + lane * 8]);
    __syncthreads();

    for (int st = 0; st < nstage; ++st) {
        const int cur = st & 1;
        if (st + 1 < nstage) {
            #pragma unroll
            for (int p = 0; p < 6; ++p)
                gl_lds16(planes + (size_t)p * M4 + base + (size_t)(st + 1) * 2048 + w * 512 + lane * 8,
                         &sm.stg[cur ^ 1][p * 2048 + w * 512 + lane * 8]);
        }
        if (st <= rt) {
            const ushort_t* sb = sm.stg[cur];
            // ---- phase 1: scores ----
            f16v accA = zero16(), accU = zero16();
            #pragma unroll
            for (int c = 0; c < 4; ++c) {
                bf8 A0 = *(const bf8*)(sb + 0 * 2048 + c * 512 + lane * 8);
                bf8 A1 = *(const bf8*)(sb + 1 * 2048 + c * 512 + lane * 8);
                bf8 A2 = *(const bf8*)(sb + 2 * 2048 + c * 512 + lane * 8);
                accA = __builtin_amdgcn_mfma_f32_32x32x16_bf16(A0, fqm[c], accA, 0, 0, 0);
                accU = __builtin_amdgcn_mfma_f32_32x32x16_bf16(A1, fvq[c], accU, 0, 0, 0);
                accU = __builtin_amdgcn_mfma_f32_32x32x16_bf16(A2, fq2[c], accU, 0, 0, 0);
            }
            if (st == rt) {                   // diagonal: mask j_loc > lh
                #pragma unroll
                for (int i = 0; i < 16; ++i) {
                    const int jl = (i & 3) + 8 * (i >> 2) + 4 * h;
                    if (jl > lh) accA[i] = -INFINITY;
                }
            }
            // ---- online softmax with defer-max ----
            float mx = accA[0];
            #pragma unroll
            for (int i = 1; i < 16; ++i) mx = fmaxf(mx, accA[i]);
            mx = fmaxf(mx, __shfl_xor(mx, 32));
            if (!__all(mx <= mrun + 8.f)) {
                const float mnew = fmaxf(mrun, mx);
                const float s1 = __expf(mrun - mnew);
                const float s2 = s1 * s1, s3 = s2 * s1;
                Zrun *= s1; S2run *= s2;
                #pragma unroll
                for (int dt = 0; dt < 2; ++dt) { vscale(aN1[dt],s1); vscale(aN2w[dt],s2); vscale(aM2[dt],s2); vscale(aN3[dt],s3); }
                mrun = mnew;
            }
            float Zt = 0.f, St = 0.f;
            #pragma unroll
            for (int i = 0; i < 16; ++i) {
                const float e = __expf(accA[i] - mrun);
                accA[i] = e;
                Zt += e; St = fmaf(e * e, accU[i], St);
            }
            Zt += __shfl_xor(Zt, 32); St += __shfl_xor(St, 32);
            Zrun += Zt; S2run += St;

            // ---- phase 2: PV ----
            #pragma unroll
            for (int c2 = 0; c2 < 2; ++c2) {
                unsigned pE[4], pE2[4], pEU[4], pE3[4];
                #pragma unroll
                for (int k = 0; k < 4; ++k) {
                    const int i0 = 8*c2 + 2*k;
                    const float e0 = accA[i0], e1 = accA[i0+1];
                    const float q0 = e0*e0, q1 = e1*e1;
                    const float t0 = q0*accU[i0], t1 = q1*accU[i0+1];
                    pE [k] = pk(e0, e1);
                    pE2[k] = pk(q0, q1);
                    pEU[k] = pk(t0, t1);
                    pE3[k] = pk(t0*e0, t1*e1);
                }
                bf8 BE  = mkB(pE [0], pE [1], pE [2], pE [3], h);
                bf8 BE2 = mkB(pE2[0], pE2[1], pE2[2], pE2[3], h);
                bf8 BEU = mkB(pEU[0], pEU[1], pEU[2], pEU[3], h);
                bf8 BE3 = mkB(pE3[0], pE3[1], pE3[2], pE3[3], h);
                #pragma unroll
                for (int dt = 0; dt < 2; ++dt) {
                    const int vo = (3 + (dt * 2 + c2) / 4 * 0) * 0;  // (placeholder removed below)
                    (void)vo;
                    const ushort_t* vp = sb + 3 * 2048 + (dt * 2 + c2) * 512 + lane * 8;
                    bf8 Am = *(const bf8*)(vp + 0 * 2048);
                    bf8 Aw = *(const bf8*)(vp + 1 * 2048);
                    bf8 Av = *(const bf8*)(vp + 2 * 2048);
                    aN1[dt]  = __builtin_amdgcn_mfma_f32_32x32x16_bf16(Am, BE,  aN1[dt],  0, 0, 0);
                    aN2w[dt] = __builtin_amdgcn_mfma_f32_32x32x16_bf16(Aw, BE2, aN2w[dt], 0, 0, 0);
                    aM2[dt]  = __builtin_amdgcn_mfma_f32_32x32x16_bf16(Aw, BEU, aM2[dt],  0, 0, 0);
                    aM2[dt]  = __builtin_amdgcn_mfma_f32_32x32x16_bf16(Av, BE2, aM2[dt],  0, 0, 0);
                    aN3[dt]  = __builtin_amdgcn_mfma_f32_32x32x16_bf16(Aw, BE3, aN3[dt],  0, 0, 0);
                }
            }
        }
        __syncthreads();
    }

    // ---- epilogue (LDS reused; all staging reads done at last barrier) ----
    const float rZ  = 1.f / Zrun;
    const float rZ2 = rZ * rZ;
    const float sS  = S2run * rZ2;
    const int b = bh >> 4, head = bh & 15;

    #pragma unroll
    for (int dt = 0; dt < 2; ++dt)
        #pragma unroll
        for (int i = 0; i < 16; ++i) {
            const int col = 32*dt + (i & 3) + 8*(i >> 2) + 4*h;
            sm.ep[w*32 + lh][col] = aN1[dt][i] * rZ;
        }
    __syncthreads();
    {
        const int row = tid >> 1, half = (tid & 1) * 32;
        const size_t o = ((size_t)b * NS + rb*128 + row) * ND + head * NDH + half;
        #pragma unroll
        for (int q4 = 0; q4 < 32; q4 += 4) {
            float4 t = make_float4(sm.ep[row][half+q4], sm.ep[row][half+q4+1],
                                   sm.ep[row][half+q4+2], sm.ep[row][half+q4+3]);
            float4 xi = *(const float4*)(x + o + q4);
            *(float4*)(out0 + o + q4) = make_float4(t.x+xi.x, t.y+xi.y, t.z+xi.z, t.w+xi.w);
        }
    }
    __syncthreads();
    #pragma unroll
    for (int dt = 0; dt < 2; ++dt)
        #pragma unroll
        for (int i = 0; i < 16; ++i) {
            const int col = 32*dt + (i & 3) + 8*(i >> 2) + 4*h;
            sm.ep[w*32 + lh][col] = rZ2 * fmaf(sS, aN2w[dt][i], aM2[dt][i]) - 2.f*rZ2*rZ*aN3[dt][i];
        }
    __syncthreads();
    {
        const int row = tid >> 1, half = (tid & 1) * 32;
        const size_t o = ((size_t)b * NS + rb*128 + row) * ND + head * NDH + half;
        #pragma unroll
        for (int q4 = 0; q4 < 32; q4 += 4) {
            float4 t = make_float4(sm.ep[row][half+q4], sm.ep[row][half+q4+1],
                                   sm.ep[row][half+q4+2], sm.ep[row][half+q4+3]);
            *(float4*)(out1 + o + q4) = t;
        }
    }
}

extern "C" void kernel_launch(void* const* d_in, const int* in_sizes, int n_in,
                              void* d_out, int out_size, void* d_ws, size_t ws_size,
                              hipStream_t stream)
{
    (void)in_sizes; (void)n_in; (void)out_size; (void)ws_size;
    const float* x  = (const float*)d_in[0];
    const float* vx = (const float*)d_in[1];
    const float* K  = (const float*)d_in[2];
    const float* VK = (const float*)d_in[3];
    const float* Vv = (const float*)d_in[4];
    const float* VV = (const float*)d_in[5];
    const float* Wm = (const float*)d_in[6];
    const float* Wv = (const float*)d_in[7];

    float* out0 = (float*)d_out;
    float* out1 = out0 + (size_t)NB * NS * ND;

    ushort_t* qm  = (ushort_t*)d_ws;
    ushort_t* vq  = qm  + M4;
    ushort_t* kmF = vq  + M4;     // 6 consecutive planes: kmF,k2F,kvF,vmF,wF,vvF
    ushort_t* k2F = kmF + M4;
    ushort_t* kvF = k2F + M4;
    ushort_t* vmF = kvF + M4;
    ushort_t* wF  = vmF + M4;
    ushort_t* vvF = wF  + M4;
    ushort_t* fxF = vvF + M4;     // 3 consecutive planes: fxF,fvxF,fx2F
    ushort_t* fvxF= fxF + M4;
    ushort_t* fx2F= fvxF+ M4;
    ushort_t* fmF = fx2F+ M4;     // 3 consecutive planes: fmF,fw2F,fvF
    ushort_t* fw2F= fmF + M1;
    ushort_t* fvF = fw2F+ M1;
    (void)k2F; (void)kvF; (void)vmF; (void)wF; (void)vvF; (void)fvxF; (void)fx2F; (void)fw2F; (void)fvF;

    prep_xw<<<2560, 256, 0, stream>>>(x, vx, Wm, Wv, fxF, fvxF, fx2F, fmF, fw2F, fvF);
    prep_kv<<<dim3(64, 32), 256, 0, stream>>>(K, VK, Vv, VV, kmF, k2F, kvF, vmF, wF, vvF);
    qproj_b<<<dim3(NH, 32), 256, 0, stream>>>(fxF, fmF, qm, vq);
    attn_b<<<512, 256, 0, stream>>>(qm, vq, kmF, x, out0, out1);
}

// Round 8
// 168.449 us; speedup vs baseline: 14.2990x; 1.0553x over previous
//
#include <hip/hip_runtime.h>
#include <hip/hip_bf16.h>
#include <math.h>

#define NB 4
#define NS 1024
#define ND 1024
#define NH 16
#define NDH 64
#define M4 4194304
#define M1 1048576

typedef float f16v __attribute__((ext_vector_type(16)));
typedef short bf8 __attribute__((ext_vector_type(8)));
typedef unsigned short ushort_t;

union U8 { bf8 v; unsigned u[4]; unsigned short s[8]; };

__device__ __forceinline__ unsigned pk(float lo, float hi) {
    __hip_bfloat162 h2 = __float22bfloat162_rn(make_float2(lo, hi));
    return *reinterpret_cast<unsigned*>(&h2);
}
__device__ __forceinline__ unsigned short f2b(float f) {
    unsigned u = __float_as_uint(f);
    unsigned r = (u + 0x7fffu + ((u >> 16) & 1u)) >> 16;   // RNE
    return (unsigned short)r;
}
__device__ __forceinline__ float b2f(unsigned short h) {
    return __uint_as_float(((unsigned)h) << 16);
}
__device__ __forceinline__ f16v zero16() {
    f16v z;
    #pragma unroll
    for (int i = 0; i < 16; ++i) z[i] = 0.f;
    return z;
}
__device__ __forceinline__ void vscale(f16v& v, float s) {
    #pragma unroll
    for (int i = 0; i < 16; ++i) v[i] *= s;
}

// async global->LDS, 16B per lane (wave-uniform base + lane*16 layout)
__device__ __forceinline__ void gl_lds16(const ushort_t* g, ushort_t* l) {
    __builtin_amdgcn_global_load_lds(
        (const __attribute__((address_space(1))) unsigned int*)g,
        (__attribute__((address_space(3))) unsigned int*)l,
        16, 0, 0);
}

// Build PV B-frag (coef[j, r], K=16 chunk) from packed pairs p0..p3.
__device__ __forceinline__ bf8 mkB(unsigned p0, unsigned p1, unsigned p2, unsigned p3, int h) {
    unsigned own0 = h ? p2 : p0;
    unsigned own1 = h ? p3 : p1;
    unsigned ct0  = h ? p0 : p2;
    unsigned ct1  = h ? p1 : p3;
    unsigned x0 = (unsigned)__shfl_xor((int)ct0, 32);
    unsigned x1 = (unsigned)__shfl_xor((int)ct1, 32);
    U8 B;
    B.u[0] = h ? x0 : own0;
    B.u[1] = h ? x1 : own1;
    B.u[2] = h ? own0 : x0;
    B.u[3] = h ? own1 : x1;
    return B.v;
}

// ===========================================================================
// Frag-order layouts (unchanged from round 7):
// K planes  [bh][s][c][lane][8]   (kmF,k2F,kvF consecutive, stride M4)
// V planes  [bh][s][dt*2+c2][lane][8] (vmF,wF,vvF consecutive, stride M4)
// x planes  [mt][kc][lane][8]     (fxF,fvxF,fx2F consecutive, stride M4)
// W planes  [nt][kc][lane][8]     (fmF,fw2F,fvF consecutive, stride M1)
// qm/vq     [bh][rt][c][lane][8]
// ===========================================================================

// merged prep: blocks [0,2048) do K/V planes; [2048, 4608) do x/W planes.
__global__ __launch_bounds__(256)
void prep_all(const float* __restrict__ x, const float* __restrict__ vx,
              const float* __restrict__ K,  const float* __restrict__ VK,
              const float* __restrict__ Vv, const float* __restrict__ VV,
              const float* __restrict__ Wm, const float* __restrict__ Wv,
              ushort_t* __restrict__ kmF, ushort_t* __restrict__ k2F, ushort_t* __restrict__ kvF,
              ushort_t* __restrict__ vmF, ushort_t* __restrict__ wF,  ushort_t* __restrict__ vvF,
              ushort_t* __restrict__ fx, ushort_t* __restrict__ fvx, ushort_t* __restrict__ fx2,
              ushort_t* __restrict__ fm, ushort_t* __restrict__ fw2, ushort_t* __restrict__ fv)
{
    __shared__ ushort_t Lm[2048], Lw[2048], Lv[2048];
    const int tid = threadIdx.x;
    const int bid = blockIdx.x;

    if (bid < 2048) {
        const int bh = bid >> 5, s = bid & 31;
        const int jp  = tid >> 3;
        const int dh0 = (tid & 7) * 8;
        const size_t gin = ((size_t)bh * NS + s * 32 + jp) * NDH + dh0;
        const size_t sbase = ((size_t)bh * 32 + s) * 2048;

        float kk[8], uu[8], vm[8], vv[8];
        *(float4*)(kk)   = *(const float4*)(K  + gin); *(float4*)(kk+4) = *(const float4*)(K  + gin + 4);
        *(float4*)(uu)   = *(const float4*)(VK + gin); *(float4*)(uu+4) = *(const float4*)(VK + gin + 4);
        *(float4*)(vm)   = *(const float4*)(Vv + gin); *(float4*)(vm+4) = *(const float4*)(Vv + gin + 4);
        *(float4*)(vv)   = *(const float4*)(VV + gin); *(float4*)(vv+4) = *(const float4*)(VV + gin + 4);

        const size_t kout = sbase + (size_t)((tid & 7) >> 1) * 512
                          + (jp + 32 * ((tid & 7) & 1)) * 8;
        unsigned o0[4], o1[4], o2[4];
        #pragma unroll
        for (int t = 0; t < 4; ++t) {
            o0[t] = pk(kk[2*t], kk[2*t+1]);
            o1[t] = pk(fmaf(kk[2*t],kk[2*t],uu[2*t]), fmaf(kk[2*t+1],kk[2*t+1],uu[2*t+1]));
            o2[t] = pk(uu[2*t], uu[2*t+1]);
        }
        *(uint4*)(kmF + kout) = make_uint4(o0[0],o0[1],o0[2],o0[3]);
        *(uint4*)(k2F + kout) = make_uint4(o1[0],o1[1],o1[2],o1[3]);
        *(uint4*)(kvF + kout) = make_uint4(o2[0],o2[1],o2[2],o2[3]);

        #pragma unroll
        for (int e = 0; e < 8; ++e) {
            const int dh = dh0 + e;
            const int idx = ((dh >> 5) * 2 + (jp >> 4)) * 512
                          + ((dh & 31) + 32 * ((jp >> 3) & 1)) * 8 + (jp & 7);
            Lm[idx] = f2b(vm[e]);
            Lw[idx] = f2b(fmaf(vm[e], vm[e], vv[e]));
            Lv[idx] = f2b(vv[e]);
        }
        __syncthreads();
        const size_t vout = sbase + (size_t)tid * 8;
        *(uint4*)(vmF + vout) = *(const uint4*)(Lm + tid * 8);
        *(uint4*)(wF  + vout) = *(const uint4*)(Lw + tid * 8);
        *(uint4*)(vvF + vout) = *(const uint4*)(Lv + tid * 8);
    } else {
        const size_t g = (size_t)(bid - 2048) * 256 + tid;
        if (g < 524288) {
            const size_t g0 = g * 8;
            const int row = (int)(g0 >> 10), k0 = (int)(g0 & 1023);
            const size_t fo = ((size_t)(row >> 5) * 64 + (k0 >> 4)) * 512
                            + ((row & 31) + 32 * ((k0 >> 3) & 1)) * 8;
            float a[8], c[8];
            *(float4*)(a)   = *(const float4*)(x + g0);  *(float4*)(a+4) = *(const float4*)(x + g0 + 4);
            *(float4*)(c)   = *(const float4*)(vx + g0); *(float4*)(c+4) = *(const float4*)(vx + g0 + 4);
            *(uint4*)(fx  + fo) = make_uint4(pk(a[0],a[1]), pk(a[2],a[3]), pk(a[4],a[5]), pk(a[6],a[7]));
            *(uint4*)(fvx + fo) = make_uint4(pk(c[0],c[1]), pk(c[2],c[3]), pk(c[4],c[5]), pk(c[6],c[7]));
            *(uint4*)(fx2 + fo) = make_uint4(pk(a[0]*a[0],a[1]*a[1]), pk(a[2]*a[2],a[3]*a[3]),
                                             pk(a[4]*a[4],a[5]*a[5]), pk(a[6]*a[6],a[7]*a[7]));
        } else {
            const size_t g0 = (g - 524288) * 8;
            const int row = (int)(g0 >> 10), k0 = (int)(g0 & 1023);
            const size_t fo = ((size_t)(row >> 5) * 64 + (k0 >> 4)) * 512
                            + ((row & 31) + 32 * ((k0 >> 3) & 1)) * 8;
            float a[8], c[8];
            *(float4*)(a)   = *(const float4*)(Wm + g0); *(float4*)(a+4) = *(const float4*)(Wm + g0 + 4);
            *(float4*)(c)   = *(const float4*)(Wv + g0); *(float4*)(c+4) = *(const float4*)(Wv + g0 + 4);
            *(uint4*)(fm  + fo) = make_uint4(pk(a[0],a[1]), pk(a[2],a[3]), pk(a[4],a[5]), pk(a[6],a[7]));
            *(uint4*)(fv  + fo) = make_uint4(pk(c[0],c[1]), pk(c[2],c[3]), pk(c[4],c[5]), pk(c[6],c[7]));
            *(uint4*)(fw2 + fo) = make_uint4(pk(fmaf(a[0],a[0],c[0]), fmaf(a[1],a[1],c[1])),
                                             pk(fmaf(a[2],a[2],c[2]), fmaf(a[3],a[3],c[3])),
                                             pk(fmaf(a[4],a[4],c[4]), fmaf(a[5],a[5],c[5])),
                                             pk(fmaf(a[6],a[6],c[6]), fmaf(a[7],a[7],c[7])));
        }
    }
}

// ---------------------------------------------------------------------------
// qproj: 4 waves share one head's W frags; triple-buffered counted-vmcnt
// pipeline (no vmcnt(0) drain in the main loop).
// ---------------------------------------------------------------------------
__global__ __launch_bounds__(256, 2)
void qproj_b(const ushort_t* __restrict__ xplanes,   // fxF (3 planes, stride M4)
             const ushort_t* __restrict__ wplanes,   // fmF (3 planes, stride M1)
             ushort_t* __restrict__ qmF, ushort_t* __restrict__ vqF)
{
    __shared__ ushort_t wstg[3][12 * 512];           // 36 KiB, 3-buf of kc-pairs

    const int tid  = threadIdx.x;
    const int w    = tid >> 6;
    const int lane = tid & 63;
    const int lh   = lane & 31;
    const int h    = lane >> 5;
    const int head = blockIdx.x;
    const int mb   = blockIdx.y;
    const int mt   = mb * 4 + w;
    const int nt   = head * 2 + (w & 1);

    f16v aQ0 = zero16(), aQ1 = zero16(), aV0 = zero16(), aV1 = zero16();

    const ushort_t* xb = xplanes + (size_t)mt * 64 * 512 + lane * 8;
    const ushort_t* wsrc = wplanes + ((size_t)nt * 64 + (w >> 1)) * 512 + lane * 8;

    // prologue: stage kc-pairs t=0 -> buf0, t=1 -> buf1
    #pragma unroll
    for (int q = 0; q < 3; ++q)
        gl_lds16(wsrc + (size_t)q * M1, &wstg[0][(3 * w + q) * 512 + lane * 8]);
    #pragma unroll
    for (int q = 0; q < 3; ++q)
        gl_lds16(wsrc + (size_t)q * M1 + 2 * 512, &wstg[1][(3 * w + q) * 512 + lane * 8]);

    for (int t = 0; t < 32; ++t) {
        const int cur = t % 3;
        if (t + 2 < 32) {
            const int nxt = (t + 2) % 3;
            #pragma unroll
            for (int q = 0; q < 3; ++q)
                gl_lds16(wsrc + (size_t)q * M1 + (size_t)(2 * (t + 2)) * 512,
                         &wstg[nxt][(3 * w + q) * 512 + lane * 8]);
            asm volatile("s_waitcnt vmcnt(6)" ::: "memory");
        } else if (t + 1 < 32) {
            asm volatile("s_waitcnt vmcnt(3)" ::: "memory");
        } else {
            asm volatile("s_waitcnt vmcnt(0)" ::: "memory");
        }
        __builtin_amdgcn_s_barrier();
        __builtin_amdgcn_sched_barrier(0);

        const ushort_t* sc = wstg[cur];
        #pragma unroll
        for (int kcL = 0; kcL < 2; ++kcL) {
            const int off = (2 * t + kcL) * 512;
            bf8 bx  = *(const bf8*)(xb + 0 * (size_t)M4 + off);
            bf8 bvx = *(const bf8*)(xb + 1 * (size_t)M4 + off);
            bf8 bx2 = *(const bf8*)(xb + 2 * (size_t)M4 + off);
            bf8 A0m = *(const bf8*)(sc + (3 * (2 * kcL + 0) + 0) * 512 + lane * 8);
            bf8 A0w = *(const bf8*)(sc + (3 * (2 * kcL + 0) + 1) * 512 + lane * 8);
            bf8 A0v = *(const bf8*)(sc + (3 * (2 * kcL + 0) + 2) * 512 + lane * 8);
            bf8 A1m = *(const bf8*)(sc + (3 * (2 * kcL + 1) + 0) * 512 + lane * 8);
            bf8 A1w = *(const bf8*)(sc + (3 * (2 * kcL + 1) + 1) * 512 + lane * 8);
            bf8 A1v = *(const bf8*)(sc + (3 * (2 * kcL + 1) + 2) * 512 + lane * 8);
            aQ0 = __builtin_amdgcn_mfma_f32_32x32x16_bf16(A0m, bx,  aQ0, 0, 0, 0);
            aV0 = __builtin_amdgcn_mfma_f32_32x32x16_bf16(A0w, bvx, aV0, 0, 0, 0);
            aV0 = __builtin_amdgcn_mfma_f32_32x32x16_bf16(A0v, bx2, aV0, 0, 0, 0);
            aQ1 = __builtin_amdgcn_mfma_f32_32x32x16_bf16(A1m, bx,  aQ1, 0, 0, 0);
            aV1 = __builtin_amdgcn_mfma_f32_32x32x16_bf16(A1w, bvx, aV1, 0, 0, 0);
            aV1 = __builtin_amdgcn_mfma_f32_32x32x16_bf16(A1v, bx2, aV1, 0, 0, 0);
        }
        __builtin_amdgcn_sched_barrier(0);
        __builtin_amdgcn_s_barrier();
    }

    const int mrow = mt * 32 + lh;
    const int b = mrow >> 10;
    const int rt = mt & 31;
    const size_t bh_base = ((size_t)(b * NH + head)) * 65536 + (size_t)rt * 2048;
    const float S1 = 0.03125f, S2 = 0.0009765625f;
    #pragma unroll
    for (int i = 0; i < 16; i += 2) {
        const int dh0 = (i & 3) + 8 * (i >> 2) + 4 * h;
        const size_t o = bh_base + (size_t)(dh0 >> 4) * 512
                       + (lh + 32 * ((dh0 >> 3) & 1)) * 8 + (dh0 & 7);
        *(unsigned*)(qmF + o)         = pk(aQ0[i]*S1, aQ0[i+1]*S1);
        *(unsigned*)(qmF + o + 1024)  = pk(aQ1[i]*S1, aQ1[i+1]*S1);
        *(unsigned*)(vqF + o)         = pk(aV0[i]*S2, aV0[i+1]*S2);
        *(unsigned*)(vqF + o + 1024)  = pk(aV1[i]*S2, aV1[i+1]*S2);
    }
}

// ---------------------------------------------------------------------------
// attn: 4 waves share K/V subtile planes; triple-buffered counted-vmcnt
// pipeline (prefetch distance 2, loads in flight across raw barriers).
// ---------------------------------------------------------------------------
__global__ __launch_bounds__(256, 2)
void attn_b(const ushort_t* __restrict__ qmF, const ushort_t* __restrict__ vqF,
            const ushort_t* __restrict__ planes,     // kmF (6 planes, stride M4)
            const float* __restrict__ x,
            float* __restrict__ out0, float* __restrict__ out1)
{
    __shared__ union {
        ushort_t stg[3][6 * 2048];   // 72 KiB staging (3-buf)
        float ep[128][66];           // epilogue scratch (reused after loop)
    } sm;

    const int tid  = threadIdx.x;
    const int w    = tid >> 6;
    const int lane = tid & 63;
    const int lh   = lane & 31;
    const int h    = lane >> 5;
    const int blk  = blockIdx.x;
    const int lb   = (blk & 7) * 64 + (blk >> 3);    // XCD-chunked
    const int rb   = 7 - (lb & 7);                   // heavy-first
    const int bh   = lb >> 3;
    const int rt   = rb * 4 + w;                     // this wave's 32-row tile
    const size_t base = (size_t)bh * 65536;

    // persistent Q frags (pre-scaled)
    bf8 fqm[4], fvq[4], fq2[4];
    {
        const ushort_t* qp = qmF + base + (size_t)rt * 2048 + lane * 8;
        const ushort_t* vp = vqF + base + (size_t)rt * 2048 + lane * 8;
        #pragma unroll
        for (int c = 0; c < 4; ++c) {
            fqm[c] = *(const bf8*)(qp + c * 512);
            fvq[c] = *(const bf8*)(vp + c * 512);
            U8 t; t.v = fqm[c];
            U8 r;
            #pragma unroll
            for (int k = 0; k < 4; ++k) {
                float q0 = b2f(t.s[2*k]), q1 = b2f(t.s[2*k+1]);
                r.u[k] = pk(q0*q0, q1*q1);
            }
            fq2[c] = r.v;
        }
    }

    f16v aN1[2], aN2w[2], aM2[2], aN3[2];
    #pragma unroll
    for (int dt = 0; dt < 2; ++dt) { aN1[dt]=zero16(); aN2w[dt]=zero16(); aM2[dt]=zero16(); aN3[dt]=zero16(); }
    float mrun = -INFINITY, Zrun = 0.f, S2run = 0.f;

    const int nstage = 4 * rb + 4;
    // prologue: stage subtiles 0 and 1 (wave w stages quarter w of each plane)
    #pragma unroll
    for (int p = 0; p < 6; ++p)
        gl_lds16(planes + (size_t)p * M4 + base + w * 512 + lane * 8,
                 &sm.stg[0][p * 2048 + w * 512 + lane * 8]);
    #pragma unroll
    for (int p = 0; p < 6; ++p)
        gl_lds16(planes + (size_t)p * M4 + base + 2048 + w * 512 + lane * 8,
                 &sm.stg[1][p * 2048 + w * 512 + lane * 8]);

    for (int st = 0; st < nstage; ++st) {
        const int cur = st % 3;
        if (st + 2 < nstage) {
            const int nxt = (st + 2) % 3;
            #pragma unroll
            for (int p = 0; p < 6; ++p)
                gl_lds16(planes + (size_t)p * M4 + base + (size_t)(st + 2) * 2048 + w * 512 + lane * 8,
                         &sm.stg[nxt][p * 2048 + w * 512 + lane * 8]);
            asm volatile("s_waitcnt vmcnt(12)" ::: "memory");
        } else if (st + 1 < nstage) {
            asm volatile("s_waitcnt vmcnt(6)" ::: "memory");
        } else {
            asm volatile("s_waitcnt vmcnt(0)" ::: "memory");
        }
        __builtin_amdgcn_s_barrier();
        __builtin_amdgcn_sched_barrier(0);

        if (st <= rt) {
            const ushort_t* sb = sm.stg[cur];
            // ---- phase 1: scores ----
            f16v accA = zero16(), accU = zero16();
            #pragma unroll
            for (int c = 0; c < 4; ++c) {
                bf8 A0 = *(const bf8*)(sb + 0 * 2048 + c * 512 + lane * 8);
                bf8 A1 = *(const bf8*)(sb + 1 * 2048 + c * 512 + lane * 8);
                bf8 A2 = *(const bf8*)(sb + 2 * 2048 + c * 512 + lane * 8);
                accA = __builtin_amdgcn_mfma_f32_32x32x16_bf16(A0, fqm[c], accA, 0, 0, 0);
                accU = __builtin_amdgcn_mfma_f32_32x32x16_bf16(A1, fvq[c], accU, 0, 0, 0);
                accU = __builtin_amdgcn_mfma_f32_32x32x16_bf16(A2, fq2[c], accU, 0, 0, 0);
            }
            if (st == rt) {                   // diagonal: mask j_loc > lh
                #pragma unroll
                for (int i = 0; i < 16; ++i) {
                    const int jl = (i & 3) + 8 * (i >> 2) + 4 * h;
                    if (jl > lh) accA[i] = -INFINITY;
                }
            }
            // ---- online softmax with defer-max ----
            float mx = accA[0];
            #pragma unroll
            for (int i = 1; i < 16; ++i) mx = fmaxf(mx, accA[i]);
            mx = fmaxf(mx, __shfl_xor(mx, 32));
            if (!__all(mx <= mrun + 8.f)) {
                const float mnew = fmaxf(mrun, mx);
                const float s1 = __expf(mrun - mnew);
                const float s2 = s1 * s1, s3 = s2 * s1;
                Zrun *= s1; S2run *= s2;
                #pragma unroll
                for (int dt = 0; dt < 2; ++dt) { vscale(aN1[dt],s1); vscale(aN2w[dt],s2); vscale(aM2[dt],s2); vscale(aN3[dt],s3); }
                mrun = mnew;
            }
            float Zt = 0.f, St = 0.f;
            #pragma unroll
            for (int i = 0; i < 16; ++i) {
                const float e = __expf(accA[i] - mrun);
                accA[i] = e;
                Zt += e; St = fmaf(e * e, accU[i], St);
            }
            Zt += __shfl_xor(Zt, 32); St += __shfl_xor(St, 32);
            Zrun += Zt; S2run += St;

            // ---- phase 2: PV ----
            #pragma unroll
            for (int c2 = 0; c2 < 2; ++c2) {
                unsigned pE[4], pE2[4], pEU[4], pE3[4];
                #pragma unroll
                for (int k = 0; k < 4; ++k) {
                    const int i0 = 8*c2 + 2*k;
                    const float e0 = accA[i0], e1 = accA[i0+1];
                    const float q0 = e0*e0, q1 = e1*e1;
                    const float t0 = q0*accU[i0], t1 = q1*accU[i0+1];
                    pE [k] = pk(e0, e1);
                    pE2[k] = pk(q0, q1);
                    pEU[k] = pk(t0, t1);
                    pE3[k] = pk(t0*e0, t1*e1);
                }
                bf8 BE  = mkB(pE [0], pE [1], pE [2], pE [3], h);
                bf8 BE2 = mkB(pE2[0], pE2[1], pE2[2], pE2[3], h);
                bf8 BEU = mkB(pEU[0], pEU[1], pEU[2], pEU[3], h);
                bf8 BE3 = mkB(pE3[0], pE3[1], pE3[2], pE3[3], h);
                #pragma unroll
                for (int dt = 0; dt < 2; ++dt) {
                    const ushort_t* vp = sb + 3 * 2048 + (dt * 2 + c2) * 512 + lane * 8;
                    bf8 Am = *(const bf8*)(vp + 0 * 2048);
                    bf8 Aw = *(const bf8*)(vp + 1 * 2048);
                    bf8 Av = *(const bf8*)(vp + 2 * 2048);
                    aN1[dt]  = __builtin_amdgcn_mfma_f32_32x32x16_bf16(Am, BE,  aN1[dt],  0, 0, 0);
                    aN2w[dt] = __builtin_amdgcn_mfma_f32_32x32x16_bf16(Aw, BE2, aN2w[dt], 0, 0, 0);
                    aM2[dt]  = __builtin_amdgcn_mfma_f32_32x32x16_bf16(Aw, BEU, aM2[dt],  0, 0, 0);
                    aM2[dt]  = __builtin_amdgcn_mfma_f32_32x32x16_bf16(Av, BE2, aM2[dt],  0, 0, 0);
                    aN3[dt]  = __builtin_amdgcn_mfma_f32_32x32x16_bf16(Aw, BE3, aN3[dt],  0, 0, 0);
                }
            }
        }
        __builtin_amdgcn_sched_barrier(0);
        __builtin_amdgcn_s_barrier();
    }

    // ---- epilogue (LDS reused; loop's last iter waited vmcnt(0) + barrier) ----
    const float rZ  = 1.f / Zrun;
    const float rZ2 = rZ * rZ;
    const float sS  = S2run * rZ2;
    const int b = bh >> 4, head = bh & 15;

    #pragma unroll
    for (int dt = 0; dt < 2; ++dt)
        #pragma unroll
        for (int i = 0; i < 16; ++i) {
            const int col = 32*dt + (i & 3) + 8*(i >> 2) + 4*h;
            sm.ep[w*32 + lh][col] = aN1[dt][i] * rZ;
        }
    __syncthreads();
    {
        const int row = tid >> 1, half = (tid & 1) * 32;
        const size_t o = ((size_t)b * NS + rb*128 + row) * ND + head * NDH + half;
        #pragma unroll
        for (int q4 = 0; q4 < 32; q4 += 4) {
            float4 t = make_float4(sm.ep[row][half+q4], sm.ep[row][half+q4+1],
                                   sm.ep[row][half+q4+2], sm.ep[row][half+q4+3]);
            float4 xi = *(const float4*)(x + o + q4);
            *(float4*)(out0 + o + q4) = make_float4(t.x+xi.x, t.y+xi.y, t.z+xi.z, t.w+xi.w);
        }
    }
    __syncthreads();
    #pragma unroll
    for (int dt = 0; dt < 2; ++dt)
        #pragma unroll
        for (int i = 0; i < 16; ++i) {
            const int col = 32*dt + (i & 3) + 8*(i >> 2) + 4*h;
            sm.ep[w*32 + lh][col] = rZ2 * fmaf(sS, aN2w[dt][i], aM2[dt][i]) - 2.f*rZ2*rZ*aN3[dt][i];
        }
    __syncthreads();
    {
        const int row = tid >> 1, half = (tid & 1) * 32;
        const size_t o = ((size_t)b * NS + rb*128 + row) * ND + head * NDH + half;
        #pragma unroll
        for (int q4 = 0; q4 < 32; q4 += 4) {
            float4 t = make_float4(sm.ep[row][half+q4], sm.ep[row][half+q4+1],
                                   sm.ep[row][half+q4+2], sm.ep[row][half+q4+3]);
            *(float4*)(out1 + o + q4) = t;
        }
    }
}

extern "C" void kernel_launch(void* const* d_in, const int* in_sizes, int n_in,
                              void* d_out, int out_size, void* d_ws, size_t ws_size,
                              hipStream_t stream)
{
    (void)in_sizes; (void)n_in; (void)out_size; (void)ws_size;
    const float* x  = (const float*)d_in[0];
    const float* vx = (const float*)d_in[1];
    const float* K  = (const float*)d_in[2];
    const float* VK = (const float*)d_in[3];
    const float* Vv = (const float*)d_in[4];
    const float* VV = (const float*)d_in[5];
    const float* Wm = (const float*)d_in[6];
    const float* Wv = (const float*)d_in[7];

    float* out0 = (float*)d_out;
    float* out1 = out0 + (size_t)NB * NS * ND;

    ushort_t* qm  = (ushort_t*)d_ws;
    ushort_t* vq  = qm  + M4;
    ushort_t* kmF = vq  + M4;     // 6 consecutive planes: kmF,k2F,kvF,vmF,wF,vvF
    ushort_t* k2F = kmF + M4;
    ushort_t* kvF = k2F + M4;
    ushort_t* vmF = kvF + M4;
    ushort_t* wF  = vmF + M4;
    ushort_t* vvF = wF  + M4;
    ushort_t* fxF = vvF + M4;     // 3 consecutive planes: fxF,fvxF,fx2F
    ushort_t* fvxF= fxF + M4;
    ushort_t* fx2F= fvxF+ M4;
    ushort_t* fmF = fx2F+ M4;     // 3 consecutive planes: fmF,fw2F,fvF
    ushort_t* fw2F= fmF + M1;
    ushort_t* fvF = fw2F+ M1;

    prep_all<<<4608, 256, 0, stream>>>(x, vx, K, VK, Vv, VV, Wm, Wv,
                                       kmF, k2F, kvF, vmF, wF, vvF,
                                       fxF, fvxF, fx2F, fmF, fw2F, fvF);
    qproj_b<<<dim3(NH, 32), 256, 0, stream>>>(fxF, fmF, qm, vq);
    attn_b<<<512, 256, 0, stream>>>(qm, vq, kmF, x, out0, out1);
}